// Round 1
// baseline (995.655 us; speedup 1.0000x reference)
//
#include <hip/hip_runtime.h>
#include <math.h>

#define BB 4
#define CC 128
#define HH 256
#define WW 256
#define NN 4000
#define NPOS 8
#define KS 3
#define HWSZ (HH*WW)

// SELU constants (jax.nn.selu)
#define SELU_ALPHA 1.6732632423543772f
#define SELU_SCALE 1.0507009873554805f
#define MAX_OFFSET 64.0f   // max(H,W)/4

__global__ __launch_bounds__(256, 4) void sddh_kernel(
    const float* __restrict__ x,         // (B,C,H,W)
    const float* __restrict__ keypoints, // (B,N,2)
    const float* __restrict__ w1,        // (16,128,3,3)
    const float* __restrict__ b1,        // (16,)
    const float* __restrict__ w2,        // (16,16)
    const float* __restrict__ b2,        // (16,)
    const float* __restrict__ wsf,       // (128,128)
    const float* __restrict__ agg,       // (8,128,128)
    float* __restrict__ out_desc,        // (B,N,128)
    float* __restrict__ out_off)         // (B,N,8,2)
{
    const int bn = blockIdx.x;           // b*N + n
    const int b  = bn / NN;
    const int t  = threadIdx.x;

    const float* xi = x + (size_t)b * CC * HWSZ;

    __shared__ float patch[CC * 9];      // [c*9 + k]
    __shared__ float conv_part[16][17];
    __shared__ float h1s[16];
    __shared__ float offs[16];
    __shared__ float feats[CC][NPOS];    // [c][p]
    __shared__ float cpart[CC][NPOS];
    __shared__ float g[CC][NPOS];        // [e][p] (post-selu features)
    __shared__ float dpart[CC];
    __shared__ float desc[CC];
    __shared__ float sq[128];
    __shared__ float kxy[2];

    // ---- keypoint -> pixel coords ----
    if (t == 0) {
        float kx = keypoints[(size_t)bn * 2 + 0];
        float ky = keypoints[(size_t)bn * 2 + 1];
        kxy[0] = (kx * 0.5f + 0.5f) * (float)(WW - 1);
        kxy[1] = (ky * 0.5f + 0.5f) * (float)(HH - 1);
    }
    __syncthreads();
    const float kwx = kxy[0];
    const float kwy = kxy[1];
    // rc = int cast (trunc); corner = trunc(rc - 0.5); clip to [0, W-1-KS]
    const int rcx = (int)kwx;
    const int rcy = (int)kwy;
    int cx = (int)truncf((float)rcx - 0.5f);
    int cy = (int)truncf((float)rcy - 0.5f);
    cx = min(max(cx, 0), WW - 1 - KS);
    cy = min(max(cy, 0), HH - 1 - KS);

    // ---- Phase A: load 128x3x3 patch ----
    for (int e = t; e < CC * 9; e += 256) {
        int c = e / 9, k = e % 9;
        int dy = k / 3, dx = k % 3;
        patch[e] = xi[(size_t)c * HWSZ + (cy + dy) * WW + (cx + dx)];
    }
    __syncthreads();

    // conv: h1[o] = relu(sum_e patch[e]*w1[o][e] + b1[o])
    {
        int o = t & 15, j = t >> 4;
        float acc = 0.f;
        const float* wo = w1 + o * (CC * 9);
        for (int e = j; e < CC * 9; e += 16) acc += patch[e] * wo[e];
        conv_part[o][j] = acc;
    }
    __syncthreads();
    if (t < 16) {
        float s = b1[t];
        #pragma unroll
        for (int j = 0; j < 16; j++) s += conv_part[t][j];
        h1s[t] = fmaxf(s, 0.f);
    }
    __syncthreads();
    // off[j] = clip(h1 . w2[j] + b2[j], -64, 64); write offsets output
    if (t < 16) {
        float s = b2[t];
        #pragma unroll
        for (int k = 0; k < 16; k++) s += h1s[k] * w2[t * 16 + k];
        s = fminf(fmaxf(s, -MAX_OFFSET), MAX_OFFSET);
        offs[t] = s;
        // layout: off[n][p][0] = flat[p], off[n][p][1] = flat[8+p]
        int idx = (t < 8) ? ((size_t)0 + bn * 16 + t * 2)
                          : (bn * 16 + (t - 8) * 2 + 1);
        out_off[idx] = s;
    }
    __syncthreads();

    // ---- Phase B: bilinear sample 128 channels x 8 positions ----
    for (int e = t; e < CC * NPOS; e += 256) {
        int c = e & 127;
        int p = e >> 7;
        float px = kwx + offs[p];
        float py = kwy + offs[8 + p];
        float x0f = floorf(px), y0f = floorf(py);
        int x0 = (int)x0f, y0 = (int)y0f;
        float wx1 = px - x0f, wx0 = 1.f - wx1;
        float wy1 = py - y0f, wy0 = 1.f - wy1;
        const float* xc = xi + (size_t)c * HWSZ;

        int x0c = min(max(x0, 0), WW - 1);
        int x1c = min(max(x0 + 1, 0), WW - 1);
        int y0c = min(max(y0, 0), HH - 1);
        int y1c = min(max(y0 + 1, 0), HH - 1);
        float vx0 = (x0 >= 0 && x0 < WW) ? 1.f : 0.f;
        float vx1 = (x0 + 1 >= 0 && x0 + 1 < WW) ? 1.f : 0.f;
        float vy0 = (y0 >= 0 && y0 < HH) ? 1.f : 0.f;
        float vy1 = (y0 + 1 >= 0 && y0 + 1 < HH) ? 1.f : 0.f;

        float v = 0.f;
        v += xc[y0c * WW + x0c] * (wx0 * wy0) * (vx0 * vy0);
        v += xc[y0c * WW + x1c] * (wx1 * wy0) * (vx1 * vy0);
        v += xc[y1c * WW + x0c] * (wx0 * wy1) * (vx0 * vy1);
        v += xc[y1c * WW + x1c] * (wx1 * wy1) * (vx1 * vy1);
        feats[c][p] = v;
    }
    __syncthreads();

    // ---- Phase C: g[d][p] = selu(sum_c feats[c][p] * wsf[d][c]) ----
    {
        int d = t & 127, chalf = t >> 7;
        float acc[NPOS];
        #pragma unroll
        for (int p = 0; p < NPOS; p++) acc[p] = 0.f;
        const float* wrow = wsf + d * CC;
        int c0 = chalf * 64;
        for (int c = c0; c < c0 + 64; c++) {
            float wv = wrow[c];
            #pragma unroll
            for (int p = 0; p < NPOS; p++) acc[p] += feats[c][p] * wv;
        }
        if (chalf) {
            #pragma unroll
            for (int p = 0; p < NPOS; p++) cpart[d][p] = acc[p];
        }
        __syncthreads();
        if (!chalf) {
            #pragma unroll
            for (int p = 0; p < NPOS; p++) {
                float s = acc[p] + cpart[d][p];
                s = (s > 0.f) ? (SELU_SCALE * s)
                              : (SELU_SCALE * SELU_ALPHA * (expf(s) - 1.f));
                g[d][p] = s;
            }
        }
    }
    __syncthreads();

    // ---- Phase D: desc[d] = sum_p sum_e g[e][p] * agg[p][e][d] ----
    {
        int d = t & 127, half = t >> 7;
        float acc = 0.f;
        int p0 = half * 4;
        for (int p = p0; p < p0 + 4; p++) {
            const float* ap = agg + (size_t)p * CC * CC;
            for (int e = 0; e < CC; e++) {
                acc += g[e][p] * ap[e * CC + d];
            }
        }
        if (half) dpart[d] = acc;
        __syncthreads();
        if (!half) {
            float v = acc + dpart[d];
            desc[d] = v;
            sq[d] = v * v;
        }
    }
    __syncthreads();

    // ---- L2 norm reduce over 128 ----
    if (t < 64) sq[t] += sq[t + 64];
    __syncthreads();
    if (t < 32) sq[t] += sq[t + 32];
    __syncthreads();
    if (t < 16) sq[t] += sq[t + 16];
    __syncthreads();
    if (t < 8) sq[t] += sq[t + 8];
    __syncthreads();
    if (t < 4) sq[t] += sq[t + 4];
    __syncthreads();
    if (t < 2) sq[t] += sq[t + 2];
    __syncthreads();
    if (t == 0) sq[0] = fmaxf(sqrtf(sq[0] + sq[1]), 1e-12f);
    __syncthreads();

    if (t < 128) {
        out_desc[(size_t)bn * CC + t] = desc[t] / sq[0];
    }
}

extern "C" void kernel_launch(void* const* d_in, const int* in_sizes, int n_in,
                              void* d_out, int out_size, void* d_ws, size_t ws_size,
                              hipStream_t stream) {
    const float* x    = (const float*)d_in[0];
    const float* kpts = (const float*)d_in[1];
    const float* w1   = (const float*)d_in[2];
    const float* b1   = (const float*)d_in[3];
    const float* w2   = (const float*)d_in[4];
    const float* b2   = (const float*)d_in[5];
    const float* wsf  = (const float*)d_in[6];
    const float* agg  = (const float*)d_in[7];

    float* out_desc = (float*)d_out;                       // B*N*128
    float* out_off  = (float*)d_out + (size_t)BB * NN * CC; // B*N*8*2

    dim3 grid(BB * NN);
    dim3 block(256);
    hipLaunchKernelGGL(sddh_kernel, grid, block, 0, stream,
                       x, kpts, w1, b1, w2, b2, wsf, agg, out_desc, out_off);
}

// Round 2
// 315.186 us; speedup vs baseline: 3.1589x; 3.1589x over previous
//
#include <hip/hip_runtime.h>
#include <math.h>

#define BB 4
#define CC 128
#define HH 256
#define WW 256
#define NN 4000
#define NPOS 8
#define KS 3
#define HWSZ (HH*WW)

#define SELU_ALPHA 1.6732632423543772f
#define SELU_SCALE 1.0507009873554805f
#define MAX_OFFSET 64.0f

#define XT_ELEMS   ((size_t)BB*HH*WW*CC)        // 33,554,432
#define FEATS_ELEMS ((size_t)BB*NN*NPOS*CC)     // 16,384,000
#define WSFT_ELEMS ((size_t)CC*CC)
#define WS_NEEDED  ((XT_ELEMS + FEATS_ELEMS + WSFT_ELEMS) * sizeof(float))

// ---------------------------------------------------------------------------
// K_T: transpose wsf (d,c) -> wsfT (c,d). Tiny.
__global__ __launch_bounds__(256) void kT_wsf(const float* __restrict__ wsf,
                                              float* __restrict__ wsfT) {
    int idx = blockIdx.x * 256 + threadIdx.x;
    if (idx < CC * CC) {
        int c = idx >> 7, d = idx & 127;
        wsfT[c * CC + d] = wsf[d * CC + c];
    }
}

// ---------------------------------------------------------------------------
// K0: transpose x (B,C,H,W) -> xt (B,H,W,C), fp32 exact.
__global__ __launch_bounds__(256) void k0_transpose(const float* __restrict__ x,
                                                    float* __restrict__ xt) {
    int blk = blockIdx.x;            // b*1024 + y*4 + xc
    int xc = blk & 3;
    int y  = (blk >> 2) & 255;
    int b  = blk >> 10;
    int x0 = xc * 64;
    const int t = threadIdx.x;
    __shared__ float lds[64][129];

    const float* xb = x + (size_t)b * CC * HWSZ + (size_t)y * WW + x0;
    for (int v = t; v < 2048; v += 256) {          // 128 c-rows x 16 float4
        int c = v >> 4, xo4 = v & 15;
        float4 val = *(const float4*)(xb + (size_t)c * HWSZ + xo4 * 4);
        lds[xo4*4+0][c] = val.x;
        lds[xo4*4+1][c] = val.y;
        lds[xo4*4+2][c] = val.z;
        lds[xo4*4+3][c] = val.w;
    }
    __syncthreads();
    float* outb = xt + ((size_t)b * HWSZ + (size_t)y * WW + x0) * CC;
    for (int v = t; v < 2048; v += 256) {          // 64 pixels x 32 float4
        int xo = v >> 5, c4 = v & 31;
        float4 val;
        val.x = lds[xo][c4*4+0];
        val.y = lds[xo][c4*4+1];
        val.z = lds[xo][c4*4+2];
        val.w = lds[xo][c4*4+3];
        *(float4*)(outb + (size_t)xo * CC + c4 * 4) = val;
    }
}

// ---------------------------------------------------------------------------
// K1: per-keypoint patch conv -> FC -> offsets -> bilinear sampling (from xt).
__global__ __launch_bounds__(256) void k1_offs_sample(
    const float* __restrict__ xt, const float* __restrict__ kpts,
    const float* __restrict__ w1, const float* __restrict__ b1,
    const float* __restrict__ w2, const float* __restrict__ b2,
    float* __restrict__ feats_ws, float* __restrict__ out_off)
{
    const int bn = blockIdx.x;
    const int b  = bn / NN;
    const int t  = threadIdx.x;
    const float* xb = xt + (size_t)b * HWSZ * CC;

    __shared__ float patch[CC * 9];      // [c*9 + k] matches w1 flat order
    __shared__ float cpart[16][17];
    __shared__ float h1s[16];
    __shared__ float offs[16];
    __shared__ float kxy[2];

    if (t == 0) {
        float kx = kpts[(size_t)bn * 2 + 0];
        float ky = kpts[(size_t)bn * 2 + 1];
        kxy[0] = (kx * 0.5f + 0.5f) * (float)(WW - 1);
        kxy[1] = (ky * 0.5f + 0.5f) * (float)(HH - 1);
    }
    __syncthreads();
    const float kwx = kxy[0], kwy = kxy[1];
    const int rcx = (int)kwx, rcy = (int)kwy;
    int cx = (int)truncf((float)rcx - 0.5f);
    int cy = (int)truncf((float)rcy - 0.5f);
    cx = min(max(cx, 0), WW - 1 - KS);
    cy = min(max(cy, 0), HH - 1 - KS);

    // patch stage: e=(k,c) -> coalesced 512B reads per pixel
    for (int e = t; e < CC * 9; e += 256) {
        int k = e >> 7, c = e & 127;
        int dy = k / 3, dx = k % 3;
        patch[c * 9 + k] = xb[((size_t)(cy + dy) * WW + (cx + dx)) * CC + c];
    }
    __syncthreads();

    {   // conv: lanes j contiguous over w1 -> coalesced weight reads
        int j = t & 15, o = t >> 4;
        const float* wo = w1 + o * (CC * 9);
        float acc = 0.f;
        for (int e = j; e < CC * 9; e += 16) acc += patch[e] * wo[e];
        cpart[o][j] = acc;
    }
    __syncthreads();
    if (t < 16) {
        float s = b1[t];
        #pragma unroll
        for (int j = 0; j < 16; j++) s += cpart[t][j];
        h1s[t] = fmaxf(s, 0.f);
    }
    __syncthreads();
    if (t < 16) {
        float s = b2[t];
        #pragma unroll
        for (int k = 0; k < 16; k++) s += h1s[k] * w2[t * 16 + k];
        s = fminf(fmaxf(s, -MAX_OFFSET), MAX_OFFSET);
        offs[t] = s;
        int idx = (t < 8) ? (bn * 16 + t * 2) : (bn * 16 + (t - 8) * 2 + 1);
        out_off[idx] = s;
    }
    __syncthreads();

    // bilinear sample: lanes c contiguous -> 512B coalesced taps
    for (int e = t; e < CC * NPOS; e += 256) {
        int p = e >> 7, c = e & 127;
        float px = kwx + offs[p];
        float py = kwy + offs[8 + p];
        float x0f = floorf(px), y0f = floorf(py);
        int x0 = (int)x0f, y0 = (int)y0f;
        float wx1 = px - x0f, wx0 = 1.f - wx1;
        float wy1 = py - y0f, wy0 = 1.f - wy1;

        int x0c = min(max(x0, 0), WW - 1);
        int x1c = min(max(x0 + 1, 0), WW - 1);
        int y0c = min(max(y0, 0), HH - 1);
        int y1c = min(max(y0 + 1, 0), HH - 1);
        float vx0 = (x0 >= 0 && x0 < WW) ? 1.f : 0.f;
        float vx1 = (x0 + 1 >= 0 && x0 + 1 < WW) ? 1.f : 0.f;
        float vy0 = (y0 >= 0 && y0 < HH) ? 1.f : 0.f;
        float vy1 = (y0 + 1 >= 0 && y0 + 1 < HH) ? 1.f : 0.f;

        float v = 0.f;
        v += xb[((size_t)y0c * WW + x0c) * CC + c] * (wx0 * wy0) * (vx0 * vy0);
        v += xb[((size_t)y0c * WW + x1c) * CC + c] * (wx1 * wy0) * (vx1 * vy0);
        v += xb[((size_t)y1c * WW + x0c) * CC + c] * (wx0 * wy1) * (vx0 * vy1);
        v += xb[((size_t)y1c * WW + x1c) * CC + c] * (wx1 * wy1) * (vx1 * vy1);
        feats_ws[(size_t)bn * (NPOS * CC) + e] = v;
    }
}

// ---------------------------------------------------------------------------
// K34: per 8-keypoint block: GEMM-C (selu) + GEMM-D (agg) + L2 norm.
__global__ __launch_bounds__(256, 4) void k34_gemm(
    const float* __restrict__ feats_ws, const float* __restrict__ wsfT,
    const float* __restrict__ agg, float* __restrict__ out_desc)
{
    const int n0 = blockIdx.x * 8;
    const int t  = threadIdx.x;
    const int d4 = t & 31;     // float4 column group
    const int grp = t >> 5;    // 0..7

    __shared__ float gbuf[64 * 132];   // feats -> g -> partials (overlaid)
    __shared__ float dsc[8 * 132];
    __shared__ float rnorm[8];

    // stage 64 feats rows (n0..n0+7) x (p 0..7), row-contig in c
    const float* frows = feats_ws + (size_t)n0 * NPOS * CC;
    for (int v = t; v < 2048; v += 256) {
        int r = v >> 5, c4 = v & 31;
        float4 val = *(const float4*)(frows + (size_t)r * CC + c4 * 4);
        float* dst = &gbuf[r * 132 + c4 * 4];
        dst[0] = val.x; dst[1] = val.y; dst[2] = val.z; dst[3] = val.w;
    }
    __syncthreads();

    // ---- GEMM C: g[r][dcol] = selu(sum_c feats[r][c] * wsf[dcol][c]) ----
    float4 acc[8];
    #pragma unroll
    for (int r8 = 0; r8 < 8; r8++) acc[r8] = make_float4(0.f, 0.f, 0.f, 0.f);
    for (int c4 = 0; c4 < 32; ++c4) {
        float4 w0 = *(const float4*)(wsfT + (c4*4+0) * CC + d4 * 4);
        float4 w1v = *(const float4*)(wsfT + (c4*4+1) * CC + d4 * 4);
        float4 w2v = *(const float4*)(wsfT + (c4*4+2) * CC + d4 * 4);
        float4 w3v = *(const float4*)(wsfT + (c4*4+3) * CC + d4 * 4);
        #pragma unroll
        for (int r8 = 0; r8 < 8; r8++) {
            const float* gp = &gbuf[(grp * 8 + r8) * 132 + c4 * 4];
            float f0 = gp[0], f1 = gp[1], f2 = gp[2], f3 = gp[3];
            acc[r8].x += f0*w0.x + f1*w1v.x + f2*w2v.x + f3*w3v.x;
            acc[r8].y += f0*w0.y + f1*w1v.y + f2*w2v.y + f3*w3v.y;
            acc[r8].z += f0*w0.z + f1*w1v.z + f2*w2v.z + f3*w3v.z;
            acc[r8].w += f0*w0.w + f1*w1v.w + f2*w2v.w + f3*w3v.w;
        }
    }
    // selu
    #pragma unroll
    for (int r8 = 0; r8 < 8; r8++) {
        float* a = (float*)&acc[r8];
        #pragma unroll
        for (int i = 0; i < 4; i++) {
            float s = a[i];
            a[i] = (s > 0.f) ? (SELU_SCALE * s)
                             : (SELU_SCALE * SELU_ALPHA * (expf(s) - 1.f));
        }
    }
    __syncthreads();
    // write g over feats (same row indexing, col = 4*d4+i)
    #pragma unroll
    for (int r8 = 0; r8 < 8; r8++) {
        float* dst = &gbuf[(grp * 8 + r8) * 132 + d4 * 4];
        dst[0] = acc[r8].x; dst[1] = acc[r8].y; dst[2] = acc[r8].z; dst[3] = acc[r8].w;
    }
    __syncthreads();

    // ---- GEMM D: partial over p = grp: desc_p[n8][dout] ----
    float4 acc2[8];
    #pragma unroll
    for (int n8 = 0; n8 < 8; n8++) acc2[n8] = make_float4(0.f, 0.f, 0.f, 0.f);
    const float* aggp = agg + (size_t)grp * CC * CC;
    for (int c4 = 0; c4 < 32; ++c4) {
        float4 a0 = *(const float4*)(aggp + (c4*4+0) * CC + d4 * 4);
        float4 a1 = *(const float4*)(aggp + (c4*4+1) * CC + d4 * 4);
        float4 a2 = *(const float4*)(aggp + (c4*4+2) * CC + d4 * 4);
        float4 a3 = *(const float4*)(aggp + (c4*4+3) * CC + d4 * 4);
        #pragma unroll
        for (int n8 = 0; n8 < 8; n8++) {
            const float* gp = &gbuf[(n8 * 8 + grp) * 132 + c4 * 4];
            float g0 = gp[0], g1 = gp[1], g2 = gp[2], g3 = gp[3];
            acc2[n8].x += g0*a0.x + g1*a1.x + g2*a2.x + g3*a3.x;
            acc2[n8].y += g0*a0.y + g1*a1.y + g2*a2.y + g3*a3.y;
            acc2[n8].z += g0*a0.z + g1*a1.z + g2*a2.z + g3*a3.z;
            acc2[n8].w += g0*a0.w + g1*a1.w + g2*a2.w + g3*a3.w;
        }
    }
    __syncthreads();
    // partials overlay: part[grp][n8][d]
    #pragma unroll
    for (int n8 = 0; n8 < 8; n8++) {
        float* dst = &gbuf[grp * 1056 + n8 * 132 + d4 * 4];
        dst[0] = acc2[n8].x; dst[1] = acc2[n8].y; dst[2] = acc2[n8].z; dst[3] = acc2[n8].w;
    }
    __syncthreads();
    // reduce 8 partials -> dsc
    for (int idx = t; idx < 1024; idx += 256) {
        int n8 = idx >> 7, d = idx & 127;
        float s = 0.f;
        #pragma unroll
        for (int g = 0; g < 8; ++g) s += gbuf[g * 1056 + n8 * 132 + d];
        dsc[n8 * 132 + d] = s;
    }
    __syncthreads();
    // norm per n8 (32-lane groups)
    {
        int n8 = t >> 5, l = t & 31;
        float s = 0.f;
        #pragma unroll
        for (int q = 0; q < 4; ++q) { float v = dsc[n8 * 132 + l + q * 32]; s += v * v; }
        s += __shfl_xor(s, 16);
        s += __shfl_xor(s, 8);
        s += __shfl_xor(s, 4);
        s += __shfl_xor(s, 2);
        s += __shfl_xor(s, 1);
        if (l == 0) rnorm[n8] = 1.0f / fmaxf(sqrtf(s), 1e-12f);
    }
    __syncthreads();
    for (int idx = t; idx < 1024; idx += 256) {
        int n8 = idx >> 7, d = idx & 127;
        out_desc[(size_t)(n0 + n8) * CC + d] = dsc[n8 * 132 + d] * rnorm[n8];
    }
}

// ---------------------------------------------------------------------------
// Fallback: original fused baseline (used only if ws is too small).
__global__ __launch_bounds__(256, 4) void sddh_baseline(
    const float* __restrict__ x, const float* __restrict__ keypoints,
    const float* __restrict__ w1, const float* __restrict__ b1,
    const float* __restrict__ w2, const float* __restrict__ b2,
    const float* __restrict__ wsf, const float* __restrict__ agg,
    float* __restrict__ out_desc, float* __restrict__ out_off)
{
    const int bn = blockIdx.x;
    const int b  = bn / NN;
    const int t  = threadIdx.x;
    const float* xi = x + (size_t)b * CC * HWSZ;

    __shared__ float patch[CC * 9];
    __shared__ float conv_part[16][17];
    __shared__ float h1s[16];
    __shared__ float offs[16];
    __shared__ float feats[CC][NPOS];
    __shared__ float cpart2[CC][NPOS];
    __shared__ float g[CC][NPOS];
    __shared__ float dpart[CC];
    __shared__ float desc[CC];
    __shared__ float sq[128];
    __shared__ float kxy[2];

    if (t == 0) {
        float kx = keypoints[(size_t)bn * 2 + 0];
        float ky = keypoints[(size_t)bn * 2 + 1];
        kxy[0] = (kx * 0.5f + 0.5f) * (float)(WW - 1);
        kxy[1] = (ky * 0.5f + 0.5f) * (float)(HH - 1);
    }
    __syncthreads();
    const float kwx = kxy[0], kwy = kxy[1];
    const int rcx = (int)kwx, rcy = (int)kwy;
    int cx = (int)truncf((float)rcx - 0.5f);
    int cy = (int)truncf((float)rcy - 0.5f);
    cx = min(max(cx, 0), WW - 1 - KS);
    cy = min(max(cy, 0), HH - 1 - KS);

    for (int e = t; e < CC * 9; e += 256) {
        int c = e / 9, k = e % 9;
        int dy = k / 3, dx = k % 3;
        patch[e] = xi[(size_t)c * HWSZ + (cy + dy) * WW + (cx + dx)];
    }
    __syncthreads();
    {
        int o = t & 15, j = t >> 4;
        float acc = 0.f;
        const float* wo = w1 + o * (CC * 9);
        for (int e = j; e < CC * 9; e += 16) acc += patch[e] * wo[e];
        conv_part[o][j] = acc;
    }
    __syncthreads();
    if (t < 16) {
        float s = b1[t];
        #pragma unroll
        for (int j = 0; j < 16; j++) s += conv_part[t][j];
        h1s[t] = fmaxf(s, 0.f);
    }
    __syncthreads();
    if (t < 16) {
        float s = b2[t];
        #pragma unroll
        for (int k = 0; k < 16; k++) s += h1s[k] * w2[t * 16 + k];
        s = fminf(fmaxf(s, -MAX_OFFSET), MAX_OFFSET);
        offs[t] = s;
        int idx = (t < 8) ? (bn * 16 + t * 2) : (bn * 16 + (t - 8) * 2 + 1);
        out_off[idx] = s;
    }
    __syncthreads();

    for (int e = t; e < CC * NPOS; e += 256) {
        int c = e & 127, p = e >> 7;
        float px = kwx + offs[p];
        float py = kwy + offs[8 + p];
        float x0f = floorf(px), y0f = floorf(py);
        int x0 = (int)x0f, y0 = (int)y0f;
        float wx1 = px - x0f, wx0 = 1.f - wx1;
        float wy1 = py - y0f, wy0 = 1.f - wy1;
        const float* xc = xi + (size_t)c * HWSZ;
        int x0c = min(max(x0, 0), WW - 1);
        int x1c = min(max(x0 + 1, 0), WW - 1);
        int y0c = min(max(y0, 0), HH - 1);
        int y1c = min(max(y0 + 1, 0), HH - 1);
        float vx0 = (x0 >= 0 && x0 < WW) ? 1.f : 0.f;
        float vx1 = (x0 + 1 >= 0 && x0 + 1 < WW) ? 1.f : 0.f;
        float vy0 = (y0 >= 0 && y0 < HH) ? 1.f : 0.f;
        float vy1 = (y0 + 1 >= 0 && y0 + 1 < HH) ? 1.f : 0.f;
        float v = 0.f;
        v += xc[y0c * WW + x0c] * (wx0 * wy0) * (vx0 * vy0);
        v += xc[y0c * WW + x1c] * (wx1 * wy0) * (vx1 * vy0);
        v += xc[y1c * WW + x0c] * (wx0 * wy1) * (vx0 * vy1);
        v += xc[y1c * WW + x1c] * (wx1 * wy1) * (vx1 * vy1);
        feats[c][p] = v;
    }
    __syncthreads();
    {
        int d = t & 127, chalf = t >> 7;
        float acc[NPOS];
        #pragma unroll
        for (int p = 0; p < NPOS; p++) acc[p] = 0.f;
        const float* wrow = wsf + d * CC;
        int c0 = chalf * 64;
        for (int c = c0; c < c0 + 64; c++) {
            float wv = wrow[c];
            #pragma unroll
            for (int p = 0; p < NPOS; p++) acc[p] += feats[c][p] * wv;
        }
        if (chalf) {
            #pragma unroll
            for (int p = 0; p < NPOS; p++) cpart2[d][p] = acc[p];
        }
        __syncthreads();
        if (!chalf) {
            #pragma unroll
            for (int p = 0; p < NPOS; p++) {
                float s = acc[p] + cpart2[d][p];
                s = (s > 0.f) ? (SELU_SCALE * s)
                              : (SELU_SCALE * SELU_ALPHA * (expf(s) - 1.f));
                g[d][p] = s;
            }
        }
    }
    __syncthreads();
    {
        int d = t & 127, half = t >> 7;
        float acc = 0.f;
        int p0 = half * 4;
        for (int p = p0; p < p0 + 4; p++) {
            const float* ap = agg + (size_t)p * CC * CC;
            for (int e = 0; e < CC; e++) acc += g[e][p] * ap[e * CC + d];
        }
        if (half) dpart[d] = acc;
        __syncthreads();
        if (!half) {
            float v = acc + dpart[d];
            desc[d] = v;
            sq[d] = v * v;
        }
    }
    __syncthreads();
    if (t < 64) sq[t] += sq[t + 64]; __syncthreads();
    if (t < 32) sq[t] += sq[t + 32]; __syncthreads();
    if (t < 16) sq[t] += sq[t + 16]; __syncthreads();
    if (t < 8)  sq[t] += sq[t + 8];  __syncthreads();
    if (t < 4)  sq[t] += sq[t + 4];  __syncthreads();
    if (t < 2)  sq[t] += sq[t + 2];  __syncthreads();
    if (t == 0) sq[0] = fmaxf(sqrtf(sq[0] + sq[1]), 1e-12f);
    __syncthreads();
    if (t < 128) out_desc[(size_t)bn * CC + t] = desc[t] / sq[0];
}

// ---------------------------------------------------------------------------
extern "C" void kernel_launch(void* const* d_in, const int* in_sizes, int n_in,
                              void* d_out, int out_size, void* d_ws, size_t ws_size,
                              hipStream_t stream) {
    const float* x    = (const float*)d_in[0];
    const float* kpts = (const float*)d_in[1];
    const float* w1   = (const float*)d_in[2];
    const float* b1   = (const float*)d_in[3];
    const float* w2   = (const float*)d_in[4];
    const float* b2   = (const float*)d_in[5];
    const float* wsf  = (const float*)d_in[6];
    const float* agg  = (const float*)d_in[7];

    float* out_desc = (float*)d_out;
    float* out_off  = (float*)d_out + (size_t)BB * NN * CC;

    if (ws_size < WS_NEEDED) {
        // fallback: proven fused baseline
        hipLaunchKernelGGL(sddh_baseline, dim3(BB * NN), dim3(256), 0, stream,
                           x, kpts, w1, b1, w2, b2, wsf, agg, out_desc, out_off);
        return;
    }

    float* xt       = (float*)d_ws;
    float* feats_ws = xt + XT_ELEMS;
    float* wsfT     = feats_ws + FEATS_ELEMS;

    hipLaunchKernelGGL(kT_wsf, dim3(64), dim3(256), 0, stream, wsf, wsfT);
    hipLaunchKernelGGL(k0_transpose, dim3(BB * HH * 4), dim3(256), 0, stream, x, xt);
    hipLaunchKernelGGL(k1_offs_sample, dim3(BB * NN), dim3(256), 0, stream,
                       xt, kpts, w1, b1, w2, b2, feats_ws, out_off);
    hipLaunchKernelGGL(k34_gemm, dim3(BB * NN / 8), dim3(256), 0, stream,
                       feats_ws, wsfT, agg, out_desc);
}

// Round 3
// 234.448 us; speedup vs baseline: 4.2468x; 1.3444x over previous
//
#include <hip/hip_runtime.h>
#include <math.h>

#define BB 4
#define CC 128
#define HH 256
#define WW 256
#define NN 4000
#define NPOS 8
#define KS 3
#define HWSZ (HH*WW)

#define SELU_ALPHA 1.6732632423543772f
#define SELU_SCALE 1.0507009873554805f
#define MAX_OFFSET 64.0f

typedef unsigned short ushort_t;
typedef short short8 __attribute__((ext_vector_type(8)));
typedef float f32x4 __attribute__((ext_vector_type(4)));

#define XT_ELEMS    ((size_t)BB*HH*WW*CC)        // 33,554,432 f32
#define FEATS_ELEMS ((size_t)BB*NN*NPOS*CC)      // 16,384,000 bf16
#define WSFBF_ELEMS ((size_t)CC*CC)              // 16,384 bf16
#define AGGT_ELEMS  ((size_t)NPOS*CC*CC)         // 131,072 bf16
#define WS_NEEDED   (XT_ELEMS*sizeof(float) + (FEATS_ELEMS+WSFBF_ELEMS+AGGT_ELEMS)*sizeof(ushort_t))

__device__ __forceinline__ ushort_t f2bf(float f) {
    unsigned u = __builtin_bit_cast(unsigned, f);
    unsigned r = (u + 0x7FFFu + ((u >> 16) & 1u)) >> 16;
    return (ushort_t)r;
}

// ---------------------------------------------------------------------------
// prep: wsf -> bf16 rows; agg (p,c,d) -> aggT (p,d,c) bf16
__global__ __launch_bounds__(256) void kprep(const float* __restrict__ wsf,
                                             const float* __restrict__ agg,
                                             ushort_t* __restrict__ wsf_bf,
                                             ushort_t* __restrict__ aggT_bf) {
    int i = blockIdx.x * 256 + threadIdx.x;
    if (i < CC * CC) wsf_bf[i] = f2bf(wsf[i]);
    if (i < NPOS * CC * CC) {
        int p = i >> 14, d = (i >> 7) & 127, c = i & 127;
        aggT_bf[i] = f2bf(agg[(p << 14) + (c << 7) + d]);
    }
}

// ---------------------------------------------------------------------------
// K0: transpose x (B,C,H,W) -> xt (B,H,W,C), fp32 exact.
__global__ __launch_bounds__(256) void k0_transpose(const float* __restrict__ x,
                                                    float* __restrict__ xt) {
    int blk = blockIdx.x;
    int xc = blk & 3;
    int y  = (blk >> 2) & 255;
    int b  = blk >> 10;
    int x0 = xc * 64;
    const int t = threadIdx.x;
    __shared__ float lds[64][129];

    const float* xb = x + (size_t)b * CC * HWSZ + (size_t)y * WW + x0;
    for (int v = t; v < 2048; v += 256) {
        int c = v >> 4, xo4 = v & 15;
        float4 val = *(const float4*)(xb + (size_t)c * HWSZ + xo4 * 4);
        lds[xo4*4+0][c] = val.x;
        lds[xo4*4+1][c] = val.y;
        lds[xo4*4+2][c] = val.z;
        lds[xo4*4+3][c] = val.w;
    }
    __syncthreads();
    float* outb = xt + ((size_t)b * HWSZ + (size_t)y * WW + x0) * CC;
    for (int v = t; v < 2048; v += 256) {
        int xo = v >> 5, c4 = v & 31;
        float4 val;
        val.x = lds[xo][c4*4+0];
        val.y = lds[xo][c4*4+1];
        val.z = lds[xo][c4*4+2];
        val.w = lds[xo][c4*4+3];
        *(float4*)(outb + (size_t)xo * CC + c4 * 4) = val;
    }
}

// ---------------------------------------------------------------------------
// K1: per-keypoint patch conv -> FC -> offsets -> bilinear sampling (from xt).
// feats written as bf16.
__global__ __launch_bounds__(256) void k1_offs_sample(
    const float* __restrict__ xt, const float* __restrict__ kpts,
    const float* __restrict__ w1, const float* __restrict__ b1,
    const float* __restrict__ w2, const float* __restrict__ b2,
    ushort_t* __restrict__ feats_bf, float* __restrict__ out_off)
{
    const int bn = blockIdx.x;
    const int b  = bn / NN;
    const int t  = threadIdx.x;
    const float* xb = xt + (size_t)b * HWSZ * CC;

    __shared__ float patch[CC * 9];
    __shared__ float cpart[16][17];
    __shared__ float h1s[16];
    __shared__ float offs[16];
    __shared__ float kxy[2];

    if (t == 0) {
        float kx = kpts[(size_t)bn * 2 + 0];
        float ky = kpts[(size_t)bn * 2 + 1];
        kxy[0] = (kx * 0.5f + 0.5f) * (float)(WW - 1);
        kxy[1] = (ky * 0.5f + 0.5f) * (float)(HH - 1);
    }
    __syncthreads();
    const float kwx = kxy[0], kwy = kxy[1];
    const int rcx = (int)kwx, rcy = (int)kwy;
    int cx = (int)truncf((float)rcx - 0.5f);
    int cy = (int)truncf((float)rcy - 0.5f);
    cx = min(max(cx, 0), WW - 1 - KS);
    cy = min(max(cy, 0), HH - 1 - KS);

    for (int e = t; e < CC * 9; e += 256) {
        int k = e >> 7, c = e & 127;
        int dy = k / 3, dx = k % 3;
        patch[c * 9 + k] = xb[((size_t)(cy + dy) * WW + (cx + dx)) * CC + c];
    }
    __syncthreads();

    {
        int j = t & 15, o = t >> 4;
        const float* wo = w1 + o * (CC * 9);
        float acc = 0.f;
        for (int e = j; e < CC * 9; e += 16) acc += patch[e] * wo[e];
        cpart[o][j] = acc;
    }
    __syncthreads();
    if (t < 16) {
        float s = b1[t];
        #pragma unroll
        for (int j = 0; j < 16; j++) s += cpart[t][j];
        h1s[t] = fmaxf(s, 0.f);
    }
    __syncthreads();
    if (t < 16) {
        float s = b2[t];
        #pragma unroll
        for (int k = 0; k < 16; k++) s += h1s[k] * w2[t * 16 + k];
        s = fminf(fmaxf(s, -MAX_OFFSET), MAX_OFFSET);
        offs[t] = s;
        int idx = (t < 8) ? (bn * 16 + t * 2) : (bn * 16 + (t - 8) * 2 + 1);
        out_off[idx] = s;
    }
    __syncthreads();

    for (int e = t; e < CC * NPOS; e += 256) {
        int p = e >> 7, c = e & 127;
        float px = kwx + offs[p];
        float py = kwy + offs[8 + p];
        float x0f = floorf(px), y0f = floorf(py);
        int x0 = (int)x0f, y0 = (int)y0f;
        float wx1 = px - x0f, wx0 = 1.f - wx1;
        float wy1 = py - y0f, wy0 = 1.f - wy1;

        int x0c = min(max(x0, 0), WW - 1);
        int x1c = min(max(x0 + 1, 0), WW - 1);
        int y0c = min(max(y0, 0), HH - 1);
        int y1c = min(max(y0 + 1, 0), HH - 1);
        float vx0 = (x0 >= 0 && x0 < WW) ? 1.f : 0.f;
        float vx1 = (x0 + 1 >= 0 && x0 + 1 < WW) ? 1.f : 0.f;
        float vy0 = (y0 >= 0 && y0 < HH) ? 1.f : 0.f;
        float vy1 = (y0 + 1 >= 0 && y0 + 1 < HH) ? 1.f : 0.f;

        float v = 0.f;
        v += xb[((size_t)y0c * WW + x0c) * CC + c] * (wx0 * wy0) * (vx0 * vy0);
        v += xb[((size_t)y0c * WW + x1c) * CC + c] * (wx1 * wy0) * (vx1 * vy0);
        v += xb[((size_t)y1c * WW + x0c) * CC + c] * (wx0 * wy1) * (vx0 * vy1);
        v += xb[((size_t)y1c * WW + x1c) * CC + c] * (wx1 * wy1) * (vx1 * vy1);
        feats_bf[(size_t)bn * (NPOS * CC) + e] = f2bf(v);
    }
}

// ---------------------------------------------------------------------------
// K34 MFMA: 16 keypoints per block (128 feat-rows). 4 waves.
// GEMM-C: g[r][d] = selu(sum_c feats[r][c]*wsf[d][c])  (128x128x128, bf16 MFMA)
// GEMM-D: desc[n][d2] = sum_{p,c} g[n*8+p][c]*aggT[p][d2][c] (16x128x1024)
__global__ __launch_bounds__(256) void k34_mfma(
    const ushort_t* __restrict__ feats_bf, const ushort_t* __restrict__ wsf_bf,
    const ushort_t* __restrict__ aggT_bf, float* __restrict__ out_desc)
{
    const int t    = threadIdx.x;
    const int wv   = t >> 6;
    const int lane = t & 63;
    const int m    = lane & 15;   // row/col within 16-tile
    const int q    = lane >> 4;   // k-subgroup (0..3)
    const int n0   = blockIdx.x * 16;
    const int R0   = n0 * NPOS;   // global feats row base

    __shared__ float g[CC * CC];      // fp32, XOR-swizzled by ((row>>3)&7)<<4
    __shared__ float dbuf[16 * 132];
    __shared__ float rn[16];

    // ---- GEMM-C ----
    for (int rti = 0; rti < 2; ++rti) {
        int rt = wv * 2 + rti;
        short8 afr[4];
        const ushort_t* arow = feats_bf + (size_t)(R0 + rt * 16 + m) * CC + q * 8;
        #pragma unroll
        for (int kk = 0; kk < 4; ++kk)
            afr[kk] = *(const short8*)(arow + kk * 32);
        for (int ct = 0; ct < 8; ++ct) {
            const ushort_t* brow = wsf_bf + (ct * 16 + m) * CC + q * 8;
            f32x4 acc = {0.f, 0.f, 0.f, 0.f};
            #pragma unroll
            for (int kk = 0; kk < 4; ++kk) {
                short8 bfr = *(const short8*)(brow + kk * 32);
                acc = __builtin_amdgcn_mfma_f32_16x16x32_bf16(afr[kk], bfr, acc, 0, 0, 0);
            }
            #pragma unroll
            for (int r = 0; r < 4; ++r) {
                float s = acc[r];
                s = (s > 0.f) ? (SELU_SCALE * s)
                              : (SELU_SCALE * SELU_ALPHA * (expf(s) - 1.f));
                int row = rt * 16 + q * 4 + r;
                int col = ct * 16 + m;
                unsigned byte = ((unsigned)(row * CC + col) << 2) ^ ((unsigned)((row >> 3) & 7) << 4);
                *(float*)((char*)g + byte) = s;
            }
        }
    }
    __syncthreads();

    // ---- GEMM-D ----
    f32x4 acc2[2];
    acc2[0] = (f32x4){0.f, 0.f, 0.f, 0.f};
    acc2[1] = (f32x4){0.f, 0.f, 0.f, 0.f};
    const int ctbase = wv * 2;
    const unsigned swz = (unsigned)(m & 7) << 4;   // (rowA>>3)&7 == m&7
    for (int kk = 0; kk < 32; ++kk) {
        int p  = kk >> 2;
        int c0 = (kk & 3) * 32 + q * 8;
        int rowA = m * 8 + p;
        unsigned lin = (unsigned)(rowA * CC + c0) << 2;
        f32x4 v0 = *(const f32x4*)((const char*)g + (lin ^ swz));
        f32x4 v1 = *(const f32x4*)((const char*)g + ((lin + 16u) ^ swz));
        short8 afr;
        #pragma unroll
        for (int j = 0; j < 4; ++j) afr[j] = (short)f2bf(v0[j]);
        #pragma unroll
        for (int j = 0; j < 4; ++j) afr[4 + j] = (short)f2bf(v1[j]);
        #pragma unroll
        for (int i = 0; i < 2; ++i) {
            int ct = ctbase + i;
            const ushort_t* brow = aggT_bf + (size_t)(p * CC + ct * 16 + m) * CC + (kk & 3) * 32 + q * 8;
            short8 bfr = *(const short8*)brow;
            acc2[i] = __builtin_amdgcn_mfma_f32_16x16x32_bf16(afr, bfr, acc2[i], 0, 0, 0);
        }
    }
    #pragma unroll
    for (int i = 0; i < 2; ++i) {
        int ct = ctbase + i;
        #pragma unroll
        for (int r = 0; r < 4; ++r) {
            int n = q * 4 + r;
            dbuf[n * 132 + ct * 16 + m] = acc2[i][r];
        }
    }
    __syncthreads();

    // ---- L2 norm (16 rows, 16 threads each) ----
    {
        int n = t >> 4, l = t & 15;
        float s = 0.f;
        #pragma unroll
        for (int j = 0; j < 8; ++j) { float v = dbuf[n * 132 + l + j * 16]; s += v * v; }
        s += __shfl_xor(s, 1);
        s += __shfl_xor(s, 2);
        s += __shfl_xor(s, 4);
        s += __shfl_xor(s, 8);
        if (l == 0) rn[n] = 1.0f / fmaxf(sqrtf(s), 1e-12f);
    }
    __syncthreads();
    for (int idx = t; idx < 2048; idx += 256) {
        int n = idx >> 7, d = idx & 127;
        out_desc[(size_t)(n0 + n) * CC + d] = dbuf[n * 132 + d] * rn[n];
    }
}

// ---------------------------------------------------------------------------
// Fallback: original fused baseline (used only if ws is too small).
__global__ __launch_bounds__(256, 4) void sddh_baseline(
    const float* __restrict__ x, const float* __restrict__ keypoints,
    const float* __restrict__ w1, const float* __restrict__ b1,
    const float* __restrict__ w2, const float* __restrict__ b2,
    const float* __restrict__ wsf, const float* __restrict__ agg,
    float* __restrict__ out_desc, float* __restrict__ out_off)
{
    const int bn = blockIdx.x;
    const int b  = bn / NN;
    const int t  = threadIdx.x;
    const float* xi = x + (size_t)b * CC * HWSZ;

    __shared__ float patch[CC * 9];
    __shared__ float conv_part[16][17];
    __shared__ float h1s[16];
    __shared__ float offs[16];
    __shared__ float feats[CC][NPOS];
    __shared__ float cpart2[CC][NPOS];
    __shared__ float g[CC][NPOS];
    __shared__ float dpart[CC];
    __shared__ float desc[CC];
    __shared__ float sq[128];
    __shared__ float kxy[2];

    if (t == 0) {
        float kx = keypoints[(size_t)bn * 2 + 0];
        float ky = keypoints[(size_t)bn * 2 + 1];
        kxy[0] = (kx * 0.5f + 0.5f) * (float)(WW - 1);
        kxy[1] = (ky * 0.5f + 0.5f) * (float)(HH - 1);
    }
    __syncthreads();
    const float kwx = kxy[0], kwy = kxy[1];
    const int rcx = (int)kwx, rcy = (int)kwy;
    int cx = (int)truncf((float)rcx - 0.5f);
    int cy = (int)truncf((float)rcy - 0.5f);
    cx = min(max(cx, 0), WW - 1 - KS);
    cy = min(max(cy, 0), HH - 1 - KS);

    for (int e = t; e < CC * 9; e += 256) {
        int c = e / 9, k = e % 9;
        int dy = k / 3, dx = k % 3;
        patch[e] = xi[(size_t)c * HWSZ + (cy + dy) * WW + (cx + dx)];
    }
    __syncthreads();
    {
        int o = t & 15, j = t >> 4;
        float acc = 0.f;
        const float* wo = w1 + o * (CC * 9);
        for (int e = j; e < CC * 9; e += 16) acc += patch[e] * wo[e];
        conv_part[o][j] = acc;
    }
    __syncthreads();
    if (t < 16) {
        float s = b1[t];
        #pragma unroll
        for (int j = 0; j < 16; j++) s += conv_part[t][j];
        h1s[t] = fmaxf(s, 0.f);
    }
    __syncthreads();
    if (t < 16) {
        float s = b2[t];
        #pragma unroll
        for (int k = 0; k < 16; k++) s += h1s[k] * w2[t * 16 + k];
        s = fminf(fmaxf(s, -MAX_OFFSET), MAX_OFFSET);
        offs[t] = s;
        int idx = (t < 8) ? (bn * 16 + t * 2) : (bn * 16 + (t - 8) * 2 + 1);
        out_off[idx] = s;
    }
    __syncthreads();

    for (int e = t; e < CC * NPOS; e += 256) {
        int c = e & 127, p = e >> 7;
        float px = kwx + offs[p];
        float py = kwy + offs[8 + p];
        float x0f = floorf(px), y0f = floorf(py);
        int x0 = (int)x0f, y0 = (int)y0f;
        float wx1 = px - x0f, wx0 = 1.f - wx1;
        float wy1 = py - y0f, wy0 = 1.f - wy1;
        const float* xc = xi + (size_t)c * HWSZ;
        int x0c = min(max(x0, 0), WW - 1);
        int x1c = min(max(x0 + 1, 0), WW - 1);
        int y0c = min(max(y0, 0), HH - 1);
        int y1c = min(max(y0 + 1, 0), HH - 1);
        float vx0 = (x0 >= 0 && x0 < WW) ? 1.f : 0.f;
        float vx1 = (x0 + 1 >= 0 && x0 + 1 < WW) ? 1.f : 0.f;
        float vy0 = (y0 >= 0 && y0 < HH) ? 1.f : 0.f;
        float vy1 = (y0 + 1 >= 0 && y0 + 1 < HH) ? 1.f : 0.f;
        float v = 0.f;
        v += xc[y0c * WW + x0c] * (wx0 * wy0) * (vx0 * vy0);
        v += xc[y0c * WW + x1c] * (wx1 * wy0) * (vx1 * vy0);
        v += xc[y1c * WW + x0c] * (wx0 * wy1) * (vx0 * vy1);
        v += xc[y1c * WW + x1c] * (wx1 * wy1) * (vx1 * vy1);
        feats[c][p] = v;
    }
    __syncthreads();
    {
        int d = t & 127, chalf = t >> 7;
        float acc[NPOS];
        #pragma unroll
        for (int p = 0; p < NPOS; p++) acc[p] = 0.f;
        const float* wrow = wsf + d * CC;
        int c0 = chalf * 64;
        for (int c = c0; c < c0 + 64; c++) {
            float wv = wrow[c];
            #pragma unroll
            for (int p = 0; p < NPOS; p++) acc[p] += feats[c][p] * wv;
        }
        if (chalf) {
            #pragma unroll
            for (int p = 0; p < NPOS; p++) cpart2[d][p] = acc[p];
        }
        __syncthreads();
        if (!chalf) {
            #pragma unroll
            for (int p = 0; p < NPOS; p++) {
                float s = acc[p] + cpart2[d][p];
                s = (s > 0.f) ? (SELU_SCALE * s)
                              : (SELU_SCALE * SELU_ALPHA * (expf(s) - 1.f));
                g[d][p] = s;
            }
        }
    }
    __syncthreads();
    {
        int d = t & 127, half = t >> 7;
        float acc = 0.f;
        int p0 = half * 4;
        for (int p = p0; p < p0 + 4; p++) {
            const float* ap = agg + (size_t)p * CC * CC;
            for (int e = 0; e < CC; e++) acc += g[e][p] * ap[e * CC + d];
        }
        if (half) dpart[d] = acc;
        __syncthreads();
        if (!half) {
            float v = acc + dpart[d];
            desc[d] = v;
            sq[d] = v * v;
        }
    }
    __syncthreads();
    if (t < 64) sq[t] += sq[t + 64]; __syncthreads();
    if (t < 32) sq[t] += sq[t + 32]; __syncthreads();
    if (t < 16) sq[t] += sq[t + 16]; __syncthreads();
    if (t < 8)  sq[t] += sq[t + 8];  __syncthreads();
    if (t < 4)  sq[t] += sq[t + 4];  __syncthreads();
    if (t < 2)  sq[t] += sq[t + 2];  __syncthreads();
    if (t == 0) sq[0] = fmaxf(sqrtf(sq[0] + sq[1]), 1e-12f);
    __syncthreads();
    if (t < 128) out_desc[(size_t)bn * CC + t] = desc[t] / sq[0];
}

// ---------------------------------------------------------------------------
extern "C" void kernel_launch(void* const* d_in, const int* in_sizes, int n_in,
                              void* d_out, int out_size, void* d_ws, size_t ws_size,
                              hipStream_t stream) {
    const float* x    = (const float*)d_in[0];
    const float* kpts = (const float*)d_in[1];
    const float* w1   = (const float*)d_in[2];
    const float* b1   = (const float*)d_in[3];
    const float* w2   = (const float*)d_in[4];
    const float* b2   = (const float*)d_in[5];
    const float* wsf  = (const float*)d_in[6];
    const float* agg  = (const float*)d_in[7];

    float* out_desc = (float*)d_out;
    float* out_off  = (float*)d_out + (size_t)BB * NN * CC;

    if (ws_size < WS_NEEDED) {
        hipLaunchKernelGGL(sddh_baseline, dim3(BB * NN), dim3(256), 0, stream,
                           x, kpts, w1, b1, w2, b2, wsf, agg, out_desc, out_off);
        return;
    }

    float*    xt       = (float*)d_ws;
    ushort_t* feats_bf = (ushort_t*)(xt + XT_ELEMS);
    ushort_t* wsf_bf   = feats_bf + FEATS_ELEMS;
    ushort_t* aggT_bf  = wsf_bf + WSFBF_ELEMS;

    hipLaunchKernelGGL(kprep, dim3(512), dim3(256), 0, stream, wsf, agg, wsf_bf, aggT_bf);
    hipLaunchKernelGGL(k0_transpose, dim3(BB * HH * 4), dim3(256), 0, stream, x, xt);
    hipLaunchKernelGGL(k1_offs_sample, dim3(BB * NN), dim3(256), 0, stream,
                       xt, kpts, w1, b1, w2, b2, feats_bf, out_off);
    hipLaunchKernelGGL(k34_mfma, dim3(BB * NN / 16), dim3(256), 0, stream,
                       feats_bf, wsf_bf, aggT_bf, out_desc);
}

// Round 4
// 121.862 us; speedup vs baseline: 8.1704x; 1.9239x over previous
//
#include <hip/hip_runtime.h>
#include <math.h>

#define BB 4
#define CC 128
#define HH 256
#define WW 256
#define NN 4000
#define NPOS 8
#define KS 3
#define HWSZ (HH*WW)

#define SELU_ALPHA 1.6732632423543772f
#define SELU_SCALE 1.0507009873554805f
#define MAX_OFFSET 64.0f

typedef unsigned short ushort_t;
typedef short short8 __attribute__((ext_vector_type(8)));
typedef float f32x4 __attribute__((ext_vector_type(4)));
typedef unsigned short ushort4_t __attribute__((ext_vector_type(4)));

#define XT_ELEMS    ((size_t)BB*HH*WW*CC)        // 33,554,432 bf16
#define FEATS_ELEMS ((size_t)BB*NN*NPOS*CC)      // 16,384,000 bf16
#define WSFBF_ELEMS ((size_t)CC*CC)              // 16,384 bf16
#define AGGT_ELEMS  ((size_t)NPOS*CC*CC)         // 131,072 bf16
#define W1T_ELEMS   ((size_t)16*CC*9)            // 18,432 bf16
#define WS_NEEDED   ((XT_ELEMS+FEATS_ELEMS+WSFBF_ELEMS+AGGT_ELEMS+W1T_ELEMS)*sizeof(ushort_t))

__device__ __forceinline__ ushort_t f2bf(float f) {
    unsigned u = __builtin_bit_cast(unsigned, f);
    unsigned r = (u + 0x7FFFu + ((u >> 16) & 1u)) >> 16;
    return (ushort_t)r;
}
__device__ __forceinline__ float bf2f(ushort_t u) {
    return __builtin_bit_cast(float, ((unsigned)u) << 16);
}

// ---------------------------------------------------------------------------
// K0P: transpose x (B,C,H,W) f32 -> xt (B,H,W,C) bf16; tail blocks do weight prep.
__global__ __launch_bounds__(256) void k0p(
    const float* __restrict__ x, ushort_t* __restrict__ xt,
    const float* __restrict__ wsf, const float* __restrict__ agg,
    const float* __restrict__ w1,
    ushort_t* __restrict__ wsf_bf, ushort_t* __restrict__ aggT_bf,
    ushort_t* __restrict__ w1t_bf)
{
    int blk = blockIdx.x;
    const int t = threadIdx.x;
    if (blk >= BB * HH * 4) {
        int i = (blk - BB * HH * 4) * 256 + t;
        if (i < CC * CC) wsf_bf[i] = f2bf(wsf[i]);
        if (i < NPOS * CC * CC) {
            int p = i >> 14, d = (i >> 7) & 127, c = i & 127;
            aggT_bf[i] = f2bf(agg[(p << 14) + (c << 7) + d]);
        }
        if (i < 16 * 1152) {
            int o = i / 1152, e = i - o * 1152, k = e >> 7, c = e & 127;
            w1t_bf[i] = f2bf(w1[o * 1152 + c * 9 + k]);
        }
        return;
    }
    int xc = blk & 3, y = (blk >> 2) & 255, b = blk >> 10;
    int x0 = xc * 64;
    __shared__ ushort_t lds[64][136];

    const float* xb = x + (size_t)b * CC * HWSZ + (size_t)y * WW + x0;
    for (int v = t; v < 2048; v += 256) {
        int c = v >> 4, xo4 = v & 15;
        float4 val = *(const float4*)(xb + (size_t)c * HWSZ + xo4 * 4);
        lds[xo4*4+0][c] = f2bf(val.x);
        lds[xo4*4+1][c] = f2bf(val.y);
        lds[xo4*4+2][c] = f2bf(val.z);
        lds[xo4*4+3][c] = f2bf(val.w);
    }
    __syncthreads();
    ushort_t* outb = xt + ((size_t)b * HWSZ + (size_t)y * WW + x0) * CC;
    for (int v = t; v < 2048; v += 256) {
        int xo = v >> 5, c4 = v & 31;
        ushort4_t val;
        val[0] = lds[xo][c4*4+0];
        val[1] = lds[xo][c4*4+1];
        val[2] = lds[xo][c4*4+2];
        val[3] = lds[xo][c4*4+3];
        *(ushort4_t*)(outb + (size_t)xo * CC + c4 * 4) = val;
    }
}

// ---------------------------------------------------------------------------
// K1: 16 keypoints per block. MFMA conv -> FC offsets -> bilinear sampling.
__global__ __launch_bounds__(256) void k1_mfma(
    const ushort_t* __restrict__ xt, const float* __restrict__ kpts,
    const ushort_t* __restrict__ w1t_bf, const float* __restrict__ b1,
    const float* __restrict__ w2, const float* __restrict__ b2,
    ushort_t* __restrict__ feats_bf, float* __restrict__ out_off)
{
    const int t  = threadIdx.x;
    const int n0 = blockIdx.x * 16;
    const int b  = n0 / NN;
    const ushort_t* xb = xt + (size_t)b * HWSZ * CC;

    __shared__ ushort_t patch[16][1160];   // [kp][k*128+c], pad 8 -> 2320B row
    __shared__ float partials[4][16][16];  // [wave][kp][o]
    __shared__ float h1f[16][17];
    __shared__ float offs[16][16];
    __shared__ float kw[16][2];
    __shared__ int   cxy[16][2];
    __shared__ int   tapoff[128][4];
    __shared__ float tapw[128][4];

    // phase 0: keypoint coords + patch corners
    if (t < 16) {
        float kx = kpts[(size_t)(n0 + t) * 2 + 0];
        float ky = kpts[(size_t)(n0 + t) * 2 + 1];
        float kwx = (kx * 0.5f + 0.5f) * (float)(WW - 1);
        float kwy = (ky * 0.5f + 0.5f) * (float)(HH - 1);
        kw[t][0] = kwx; kw[t][1] = kwy;
        int rcx = (int)kwx, rcy = (int)kwy;
        int cx = (int)truncf((float)rcx - 0.5f);
        int cy = (int)truncf((float)rcy - 0.5f);
        cxy[t][0] = min(max(cx, 0), WW - 1 - KS);
        cxy[t][1] = min(max(cy, 0), HH - 1 - KS);
    }
    __syncthreads();

    // phase 1: gather 16 patches (bf16 raw copy), 4608 ushort4 tasks
    #pragma unroll
    for (int it = 0; it < 18; ++it) {
        int v = it * 256 + t;
        int kp = v / 288;
        int rem = v - kp * 288;
        int k = rem >> 5, c4 = rem & 31;
        int kd = k / 3;
        int px = cxy[kp][0] + (k - kd * 3);
        int py = cxy[kp][1] + kd;
        ushort4_t val = *(const ushort4_t*)(xb + ((size_t)(py * WW + px) * CC) + c4 * 4);
        *(ushort4_t*)&patch[kp][k * 128 + c4 * 4] = val;
    }
    __syncthreads();

    // phase 2: conv via MFMA. A=patch rows (kp), B=w1t rows (o). K split over waves.
    {
        int wv = t >> 6, lane = t & 63, m = lane & 15, q = lane >> 4;
        f32x4 hacc = {0.f, 0.f, 0.f, 0.f};
        const ushort_t* arow = &patch[m][wv * 288 + q * 8];
        const ushort_t* brow = w1t_bf + m * 1152 + wv * 288 + q * 8;
        #pragma unroll
        for (int kk = 0; kk < 9; ++kk) {
            short8 a   = *(const short8*)(arow + kk * 32);
            short8 bfr = *(const short8*)(brow + kk * 32);
            hacc = __builtin_amdgcn_mfma_f32_16x16x32_bf16(a, bfr, hacc, 0, 0, 0);
        }
        #pragma unroll
        for (int r = 0; r < 4; ++r) partials[wv][q * 4 + r][m] = hacc[r];
    }
    __syncthreads();
    {   // reduce K-partials + bias + relu
        int kp = t >> 4, o = t & 15;
        float h = partials[0][kp][o] + partials[1][kp][o]
                + partials[2][kp][o] + partials[3][kp][o] + b1[o];
        h1f[kp][o] = fmaxf(h, 0.f);
    }
    __syncthreads();
    {   // FC: off[kp][j] = clip(h1 . w2[j] + b2[j])
        int kp = t >> 4, j = t & 15;
        float s = b2[j];
        #pragma unroll
        for (int o = 0; o < 16; ++o) s += h1f[kp][o] * w2[j * 16 + o];
        s = fminf(fmaxf(s, -MAX_OFFSET), MAX_OFFSET);
        offs[kp][j] = s;
        int p = j & 7, comp = j >> 3;
        out_off[((size_t)(n0 + kp) * 8 + p) * 2 + comp] = s;
    }
    __syncthreads();

    // phase 3: coords/weights once per (kp,p)
    if (t < 128) {
        int kp = t >> 3, p = t & 7;
        float px = kw[kp][0] + offs[kp][p];
        float py = kw[kp][1] + offs[kp][8 + p];
        float x0f = floorf(px), y0f = floorf(py);
        int x0 = (int)x0f, y0 = (int)y0f;
        float wx1 = px - x0f, wx0 = 1.f - wx1;
        float wy1 = py - y0f, wy0 = 1.f - wy1;
        int x0c = min(max(x0, 0), WW - 1);
        int x1c = min(max(x0 + 1, 0), WW - 1);
        int y0c = min(max(y0, 0), HH - 1);
        int y1c = min(max(y0 + 1, 0), HH - 1);
        float vx0 = (x0 >= 0 && x0 < WW) ? 1.f : 0.f;
        float vx1 = (x0 + 1 >= 0 && x0 + 1 < WW) ? 1.f : 0.f;
        float vy0 = (y0 >= 0 && y0 < HH) ? 1.f : 0.f;
        float vy1 = (y0 + 1 >= 0 && y0 + 1 < HH) ? 1.f : 0.f;
        tapoff[t][0] = (y0c * WW + x0c) * CC;
        tapoff[t][1] = (y0c * WW + x1c) * CC;
        tapoff[t][2] = (y1c * WW + x0c) * CC;
        tapoff[t][3] = (y1c * WW + x1c) * CC;
        tapw[t][0] = wx0 * wy0 * vx0 * vy0;
        tapw[t][1] = wx1 * wy0 * vx1 * vy0;
        tapw[t][2] = wx0 * wy1 * vx0 * vy1;
        tapw[t][3] = wx1 * wy1 * vx1 * vy1;
    }
    __syncthreads();

    // phase 4: bilinear, 2 threads per (kp,p), 16 channel-quads each
    {
        int pair = t >> 1, half = t & 1;
        int kp = pair >> 3, p = pair & 7;
        const ushort_t* s0 = xb + tapoff[pair][0];
        const ushort_t* s1 = xb + tapoff[pair][1];
        const ushort_t* s2 = xb + tapoff[pair][2];
        const ushort_t* s3 = xb + tapoff[pair][3];
        float w00 = tapw[pair][0], w01 = tapw[pair][1];
        float w10 = tapw[pair][2], w11 = tapw[pair][3];
        ushort_t* dst = feats_bf + (size_t)(n0 + kp) * (NPOS * CC) + p * CC + half * 64;
        #pragma unroll
        for (int i = 0; i < 16; ++i) {
            int c = half * 64 + i * 4;
            ushort4_t t0 = *(const ushort4_t*)(s0 + c);
            ushort4_t t1 = *(const ushort4_t*)(s1 + c);
            ushort4_t t2 = *(const ushort4_t*)(s2 + c);
            ushort4_t t3 = *(const ushort4_t*)(s3 + c);
            ushort4_t r;
            #pragma unroll
            for (int j = 0; j < 4; ++j) {
                float v = bf2f(t0[j]) * w00 + bf2f(t1[j]) * w01
                        + bf2f(t2[j]) * w10 + bf2f(t3[j]) * w11;
                r[j] = f2bf(v);
            }
            *(ushort4_t*)(dst + i * 4) = r;
        }
    }
}

// ---------------------------------------------------------------------------
// K34 MFMA: 16 keypoints per block (128 feat-rows). 4 waves. (unchanged, verified)
__global__ __launch_bounds__(256) void k34_mfma(
    const ushort_t* __restrict__ feats_bf, const ushort_t* __restrict__ wsf_bf,
    const ushort_t* __restrict__ aggT_bf, float* __restrict__ out_desc)
{
    const int t    = threadIdx.x;
    const int wv   = t >> 6;
    const int lane = t & 63;
    const int m    = lane & 15;
    const int q    = lane >> 4;
    const int n0   = blockIdx.x * 16;
    const int R0   = n0 * NPOS;

    __shared__ float g[CC * CC];
    __shared__ float dbuf[16 * 132];
    __shared__ float rn[16];

    for (int rti = 0; rti < 2; ++rti) {
        int rt = wv * 2 + rti;
        short8 afr[4];
        const ushort_t* arow = feats_bf + (size_t)(R0 + rt * 16 + m) * CC + q * 8;
        #pragma unroll
        for (int kk = 0; kk < 4; ++kk)
            afr[kk] = *(const short8*)(arow + kk * 32);
        for (int ct = 0; ct < 8; ++ct) {
            const ushort_t* brow = wsf_bf + (ct * 16 + m) * CC + q * 8;
            f32x4 acc = {0.f, 0.f, 0.f, 0.f};
            #pragma unroll
            for (int kk = 0; kk < 4; ++kk) {
                short8 bfr = *(const short8*)(brow + kk * 32);
                acc = __builtin_amdgcn_mfma_f32_16x16x32_bf16(afr[kk], bfr, acc, 0, 0, 0);
            }
            #pragma unroll
            for (int r = 0; r < 4; ++r) {
                float s = acc[r];
                s = (s > 0.f) ? (SELU_SCALE * s)
                              : (SELU_SCALE * SELU_ALPHA * (expf(s) - 1.f));
                int row = rt * 16 + q * 4 + r;
                int col = ct * 16 + m;
                unsigned byte = ((unsigned)(row * CC + col) << 2) ^ ((unsigned)((row >> 3) & 7) << 4);
                *(float*)((char*)g + byte) = s;
            }
        }
    }
    __syncthreads();

    f32x4 acc2[2];
    acc2[0] = (f32x4){0.f, 0.f, 0.f, 0.f};
    acc2[1] = (f32x4){0.f, 0.f, 0.f, 0.f};
    const int ctbase = wv * 2;
    const unsigned swz = (unsigned)(m & 7) << 4;
    for (int kk = 0; kk < 32; ++kk) {
        int p  = kk >> 2;
        int c0 = (kk & 3) * 32 + q * 8;
        int rowA = m * 8 + p;
        unsigned lin = (unsigned)(rowA * CC + c0) << 2;
        f32x4 v0 = *(const f32x4*)((const char*)g + (lin ^ swz));
        f32x4 v1 = *(const f32x4*)((const char*)g + ((lin + 16u) ^ swz));
        short8 afr;
        #pragma unroll
        for (int j = 0; j < 4; ++j) afr[j] = (short)f2bf(v0[j]);
        #pragma unroll
        for (int j = 0; j < 4; ++j) afr[4 + j] = (short)f2bf(v1[j]);
        #pragma unroll
        for (int i = 0; i < 2; ++i) {
            int ct = ctbase + i;
            const ushort_t* brow = aggT_bf + (size_t)(p * CC + ct * 16 + m) * CC + (kk & 3) * 32 + q * 8;
            short8 bfr = *(const short8*)brow;
            acc2[i] = __builtin_amdgcn_mfma_f32_16x16x32_bf16(afr, bfr, acc2[i], 0, 0, 0);
        }
    }
    #pragma unroll
    for (int i = 0; i < 2; ++i) {
        int ct = ctbase + i;
        #pragma unroll
        for (int r = 0; r < 4; ++r) {
            int n = q * 4 + r;
            dbuf[n * 132 + ct * 16 + m] = acc2[i][r];
        }
    }
    __syncthreads();

    {
        int n = t >> 4, l = t & 15;
        float s = 0.f;
        #pragma unroll
        for (int j = 0; j < 8; ++j) { float v = dbuf[n * 132 + l + j * 16]; s += v * v; }
        s += __shfl_xor(s, 1);
        s += __shfl_xor(s, 2);
        s += __shfl_xor(s, 4);
        s += __shfl_xor(s, 8);
        if (l == 0) rn[n] = 1.0f / fmaxf(sqrtf(s), 1e-12f);
    }
    __syncthreads();
    for (int idx = t; idx < 2048; idx += 256) {
        int n = idx >> 7, d = idx & 127;
        out_desc[(size_t)(n0 + n) * CC + d] = dbuf[n * 132 + d] * rn[n];
    }
}

// ---------------------------------------------------------------------------
// Fallback: original fused baseline (used only if ws is too small).
__global__ __launch_bounds__(256, 4) void sddh_baseline(
    const float* __restrict__ x, const float* __restrict__ keypoints,
    const float* __restrict__ w1, const float* __restrict__ b1,
    const float* __restrict__ w2, const float* __restrict__ b2,
    const float* __restrict__ wsf, const float* __restrict__ agg,
    float* __restrict__ out_desc, float* __restrict__ out_off)
{
    const int bn = blockIdx.x;
    const int b  = bn / NN;
    const int t  = threadIdx.x;
    const float* xi = x + (size_t)b * CC * HWSZ;

    __shared__ float patch[CC * 9];
    __shared__ float conv_part[16][17];
    __shared__ float h1s[16];
    __shared__ float offs[16];
    __shared__ float feats[CC][NPOS];
    __shared__ float cpart2[CC][NPOS];
    __shared__ float g[CC][NPOS];
    __shared__ float dpart[CC];
    __shared__ float desc[CC];
    __shared__ float sq[128];
    __shared__ float kxy[2];

    if (t == 0) {
        float kx = keypoints[(size_t)bn * 2 + 0];
        float ky = keypoints[(size_t)bn * 2 + 1];
        kxy[0] = (kx * 0.5f + 0.5f) * (float)(WW - 1);
        kxy[1] = (ky * 0.5f + 0.5f) * (float)(HH - 1);
    }
    __syncthreads();
    const float kwx = kxy[0], kwy = kxy[1];
    const int rcx = (int)kwx, rcy = (int)kwy;
    int cx = (int)truncf((float)rcx - 0.5f);
    int cy = (int)truncf((float)rcy - 0.5f);
    cx = min(max(cx, 0), WW - 1 - KS);
    cy = min(max(cy, 0), HH - 1 - KS);

    for (int e = t; e < CC * 9; e += 256) {
        int c = e / 9, k = e % 9;
        int dy = k / 3, dx = k % 3;
        patch[e] = xi[(size_t)c * HWSZ + (cy + dy) * WW + (cx + dx)];
    }
    __syncthreads();
    {
        int o = t & 15, j = t >> 4;
        float acc = 0.f;
        const float* wo = w1 + o * (CC * 9);
        for (int e = j; e < CC * 9; e += 16) acc += patch[e] * wo[e];
        conv_part[o][j] = acc;
    }
    __syncthreads();
    if (t < 16) {
        float s = b1[t];
        #pragma unroll
        for (int j = 0; j < 16; j++) s += conv_part[t][j];
        h1s[t] = fmaxf(s, 0.f);
    }
    __syncthreads();
    if (t < 16) {
        float s = b2[t];
        #pragma unroll
        for (int k = 0; k < 16; k++) s += h1s[k] * w2[t * 16 + k];
        s = fminf(fmaxf(s, -MAX_OFFSET), MAX_OFFSET);
        offs[t] = s;
        int idx = (t < 8) ? (bn * 16 + t * 2) : (bn * 16 + (t - 8) * 2 + 1);
        out_off[idx] = s;
    }
    __syncthreads();

    for (int e = t; e < CC * NPOS; e += 256) {
        int c = e & 127, p = e >> 7;
        float px = kwx + offs[p];
        float py = kwy + offs[8 + p];
        float x0f = floorf(px), y0f = floorf(py);
        int x0 = (int)x0f, y0 = (int)y0f;
        float wx1 = px - x0f, wx0 = 1.f - wx1;
        float wy1 = py - y0f, wy0 = 1.f - wy1;
        const float* xc = xi + (size_t)c * HWSZ;
        int x0c = min(max(x0, 0), WW - 1);
        int x1c = min(max(x0 + 1, 0), WW - 1);
        int y0c = min(max(y0, 0), HH - 1);
        int y1c = min(max(y0 + 1, 0), HH - 1);
        float vx0 = (x0 >= 0 && x0 < WW) ? 1.f : 0.f;
        float vx1 = (x0 + 1 >= 0 && x0 + 1 < WW) ? 1.f : 0.f;
        float vy0 = (y0 >= 0 && y0 < HH) ? 1.f : 0.f;
        float vy1 = (y0 + 1 >= 0 && y0 + 1 < HH) ? 1.f : 0.f;
        float v = 0.f;
        v += xc[y0c * WW + x0c] * (wx0 * wy0) * (vx0 * vy0);
        v += xc[y0c * WW + x1c] * (wx1 * wy0) * (vx1 * vy0);
        v += xc[y1c * WW + x0c] * (wx0 * wy1) * (vx0 * vy1);
        v += xc[y1c * WW + x1c] * (wx1 * wy1) * (vx1 * vy1);
        feats[c][p] = v;
    }
    __syncthreads();
    {
        int d = t & 127, chalf = t >> 7;
        float acc[NPOS];
        #pragma unroll
        for (int p = 0; p < NPOS; p++) acc[p] = 0.f;
        const float* wrow = wsf + d * CC;
        int c0 = chalf * 64;
        for (int c = c0; c < c0 + 64; c++) {
            float wv = wrow[c];
            #pragma unroll
            for (int p = 0; p < NPOS; p++) acc[p] += feats[c][p] * wv;
        }
        if (chalf) {
            #pragma unroll
            for (int p = 0; p < NPOS; p++) cpart2[d][p] = acc[p];
        }
        __syncthreads();
        if (!chalf) {
            #pragma unroll
            for (int p = 0; p < NPOS; p++) {
                float s = acc[p] + cpart2[d][p];
                s = (s > 0.f) ? (SELU_SCALE * s)
                              : (SELU_SCALE * SELU_ALPHA * (expf(s) - 1.f));
                g[d][p] = s;
            }
        }
    }
    __syncthreads();
    {
        int d = t & 127, half = t >> 7;
        float acc = 0.f;
        int p0 = half * 4;
        for (int p = p0; p < p0 + 4; p++) {
            const float* ap = agg + (size_t)p * CC * CC;
            for (int e = 0; e < CC; e++) acc += g[e][p] * ap[e * CC + d];
        }
        if (half) dpart[d] = acc;
        __syncthreads();
        if (!half) {
            float v = acc + dpart[d];
            desc[d] = v;
            sq[d] = v * v;
        }
    }
    __syncthreads();
    if (t < 64) sq[t] += sq[t + 64]; __syncthreads();
    if (t < 32) sq[t] += sq[t + 32]; __syncthreads();
    if (t < 16) sq[t] += sq[t + 16]; __syncthreads();
    if (t < 8)  sq[t] += sq[t + 8];  __syncthreads();
    if (t < 4)  sq[t] += sq[t + 4];  __syncthreads();
    if (t < 2)  sq[t] += sq[t + 2];  __syncthreads();
    if (t == 0) sq[0] = fmaxf(sqrtf(sq[0] + sq[1]), 1e-12f);
    __syncthreads();
    if (t < 128) out_desc[(size_t)bn * CC + t] = desc[t] / sq[0];
}

// ---------------------------------------------------------------------------
extern "C" void kernel_launch(void* const* d_in, const int* in_sizes, int n_in,
                              void* d_out, int out_size, void* d_ws, size_t ws_size,
                              hipStream_t stream) {
    const float* x    = (const float*)d_in[0];
    const float* kpts = (const float*)d_in[1];
    const float* w1   = (const float*)d_in[2];
    const float* b1   = (const float*)d_in[3];
    const float* w2   = (const float*)d_in[4];
    const float* b2   = (const float*)d_in[5];
    const float* wsf  = (const float*)d_in[6];
    const float* agg  = (const float*)d_in[7];

    float* out_desc = (float*)d_out;
    float* out_off  = (float*)d_out + (size_t)BB * NN * CC;

    if (ws_size < WS_NEEDED) {
        hipLaunchKernelGGL(sddh_baseline, dim3(BB * NN), dim3(256), 0, stream,
                           x, kpts, w1, b1, w2, b2, wsf, agg, out_desc, out_off);
        return;
    }

    ushort_t* xt       = (ushort_t*)d_ws;
    ushort_t* feats_bf = xt + XT_ELEMS;
    ushort_t* wsf_bf   = feats_bf + FEATS_ELEMS;
    ushort_t* aggT_bf  = wsf_bf + WSFBF_ELEMS;
    ushort_t* w1t_bf   = aggT_bf + AGGT_ELEMS;

    hipLaunchKernelGGL(k0p, dim3(BB * HH * 4 + 512), dim3(256), 0, stream,
                       x, xt, wsf, agg, w1, wsf_bf, aggT_bf, w1t_bf);
    hipLaunchKernelGGL(k1_mfma, dim3(BB * NN / 16), dim3(256), 0, stream,
                       xt, kpts, w1t_bf, b1, w2, b2, feats_bf, out_off);
    hipLaunchKernelGGL(k34_mfma, dim3(BB * NN / 16), dim3(256), 0, stream,
                       feats_bf, wsf_bf, aggT_bf, out_desc);
}

// Round 5
// 106.792 us; speedup vs baseline: 9.3233x; 1.1411x over previous
//
#include <hip/hip_runtime.h>
#include <math.h>

#define BB 4
#define CC 128
#define HH 256
#define WW 256
#define NN 4000
#define NPOS 8
#define KS 3
#define HWSZ (HH*WW)

#define SELU_ALPHA 1.6732632423543772f
#define SELU_SCALE 1.0507009873554805f
#define MAX_OFFSET 64.0f

typedef unsigned short ushort_t;
typedef short short8 __attribute__((ext_vector_type(8)));
typedef float f32x4 __attribute__((ext_vector_type(4)));
typedef unsigned short ushort4_t __attribute__((ext_vector_type(4)));

#define XT_ELEMS    ((size_t)BB*HH*WW*CC)        // 33,554,432 bf16
#define WSFBF_ELEMS ((size_t)CC*CC)              // 16,384 bf16
#define AGGT_ELEMS  ((size_t)NPOS*CC*CC)         // 131,072 bf16
#define W1T_ELEMS   ((size_t)16*CC*9)            // 18,432 bf16
#define WS_NEEDED   ((XT_ELEMS+WSFBF_ELEMS+AGGT_ELEMS+W1T_ELEMS)*sizeof(ushort_t))

__device__ __forceinline__ ushort_t f2bf(float f) {
    unsigned u = __builtin_bit_cast(unsigned, f);
    unsigned r = (u + 0x7FFFu + ((u >> 16) & 1u)) >> 16;
    return (ushort_t)r;
}
__device__ __forceinline__ float bf2f(ushort_t u) {
    return __builtin_bit_cast(float, ((unsigned)u) << 16);
}

// ---------------------------------------------------------------------------
// K0P: transpose x (B,C,H,W) f32 -> xt (B,H,W,C) bf16; tail blocks do weight prep.
__global__ __launch_bounds__(256) void k0p(
    const float* __restrict__ x, ushort_t* __restrict__ xt,
    const float* __restrict__ wsf, const float* __restrict__ agg,
    const float* __restrict__ w1,
    ushort_t* __restrict__ wsf_bf, ushort_t* __restrict__ aggT_bf,
    ushort_t* __restrict__ w1t_bf)
{
    int blk = blockIdx.x;
    const int t = threadIdx.x;
    if (blk >= BB * HH * 4) {
        int i = (blk - BB * HH * 4) * 256 + t;
        if (i < CC * CC) wsf_bf[i] = f2bf(wsf[i]);
        if (i < NPOS * CC * CC) {
            int p = i >> 14, d = (i >> 7) & 127, c = i & 127;
            aggT_bf[i] = f2bf(agg[(p << 14) + (c << 7) + d]);
        }
        if (i < 16 * 1152) {
            int o = i / 1152, e = i - o * 1152, k = e >> 7, c = e & 127;
            w1t_bf[i] = f2bf(w1[o * 1152 + c * 9 + k]);
        }
        return;
    }
    int xc = blk & 3, y = (blk >> 2) & 255, b = blk >> 10;
    int x0 = xc * 64;
    __shared__ ushort_t lds[64][136];

    const float* xb = x + (size_t)b * CC * HWSZ + (size_t)y * WW + x0;
    for (int v = t; v < 2048; v += 256) {
        int c = v >> 4, xo4 = v & 15;
        float4 val = *(const float4*)(xb + (size_t)c * HWSZ + xo4 * 4);
        lds[xo4*4+0][c] = f2bf(val.x);
        lds[xo4*4+1][c] = f2bf(val.y);
        lds[xo4*4+2][c] = f2bf(val.z);
        lds[xo4*4+3][c] = f2bf(val.w);
    }
    __syncthreads();
    ushort_t* outb = xt + ((size_t)b * HWSZ + (size_t)y * WW + x0) * CC;
    for (int v = t; v < 2048; v += 256) {
        int xo = v >> 5, c4 = v & 31;
        ushort4_t val;
        val[0] = lds[xo][c4*4+0];
        val[1] = lds[xo][c4*4+1];
        val[2] = lds[xo][c4*4+2];
        val[3] = lds[xo][c4*4+3];
        *(ushort4_t*)(outb + (size_t)xo * CC + c4 * 4) = val;
    }
}

// ---------------------------------------------------------------------------
// K14 fused: per 16 keypoints: conv(MFMA, A from global) -> FC offsets ->
// bilinear -> feats(LDS bf16, swz r&7) -> GEMM-C(selu -> g LDS bf16, swz row>>3)
// -> GEMM-D(aggT) -> L2 norm.
__global__ __launch_bounds__(256, 2) void k14_fused(
    const ushort_t* __restrict__ xt, const float* __restrict__ kpts,
    const ushort_t* __restrict__ w1t_bf, const float* __restrict__ b1,
    const float* __restrict__ w2, const float* __restrict__ b2,
    const ushort_t* __restrict__ wsf_bf, const ushort_t* __restrict__ aggT_bf,
    float* __restrict__ out_desc, float* __restrict__ out_off)
{
    const int t    = threadIdx.x;
    const int wv   = t >> 6;
    const int lane = t & 63;
    const int m    = lane & 15;
    const int q    = lane >> 4;
    const int n0   = blockIdx.x * 16;
    const int b    = n0 / NN;
    const ushort_t* xb = xt + (size_t)b * HWSZ * CC;

    __shared__ ushort_t feats[CC * CC];   // bf16, byte swz: ^((r&7)<<4)
    __shared__ ushort_t g[CC * CC];       // bf16, byte swz: ^(((row>>3)&7)<<4)
    __shared__ union {
        struct {
            float partials[4][16][16];
            float h1f[16][17];
            float offs[16][16];
            int   tapoff[128][4];
            float tapw[128][4];
        } a;
        float dbuf[16 * 132];
    } u;
    __shared__ float kw[16][2];
    __shared__ int   cxy[16][2];
    __shared__ float rn[16];

    // ---- phase 0: keypoint coords + patch corners ----
    if (t < 16) {
        float kx = kpts[(size_t)(n0 + t) * 2 + 0];
        float ky = kpts[(size_t)(n0 + t) * 2 + 1];
        float kwx = (kx * 0.5f + 0.5f) * (float)(WW - 1);
        float kwy = (ky * 0.5f + 0.5f) * (float)(HH - 1);
        kw[t][0] = kwx; kw[t][1] = kwy;
        int rcx = (int)kwx, rcy = (int)kwy;
        int cx = (int)truncf((float)rcx - 0.5f);
        int cy = (int)truncf((float)rcy - 0.5f);
        cxy[t][0] = min(max(cx, 0), WW - 1 - KS);
        cxy[t][1] = min(max(cy, 0), HH - 1 - KS);
    }
    __syncthreads();

    // ---- phase 1: conv via MFMA, A-fragments directly from global xt ----
    {
        int px0 = cxy[m][0], py0 = cxy[m][1];
        f32x4 hacc = {0.f, 0.f, 0.f, 0.f};
        const ushort_t* brow = w1t_bf + m * 1152 + wv * 288 + q * 8;
        #pragma unroll
        for (int kk = 0; kk < 9; ++kk) {
            int e = wv * 288 + kk * 32 + q * 8;
            int k = e >> 7, c = e & 127;
            int kd = k / 3, kx2 = k - kd * 3;
            const ushort_t* src = xb + ((size_t)((py0 + kd) * WW + px0 + kx2)) * CC + c;
            short8 a   = *(const short8*)src;
            short8 bfr = *(const short8*)(brow + kk * 32);
            hacc = __builtin_amdgcn_mfma_f32_16x16x32_bf16(a, bfr, hacc, 0, 0, 0);
        }
        #pragma unroll
        for (int r = 0; r < 4; ++r) u.a.partials[wv][q * 4 + r][m] = hacc[r];
    }
    __syncthreads();
    {   // reduce K-partials + bias + relu
        int kp = t >> 4, o = t & 15;
        float h = u.a.partials[0][kp][o] + u.a.partials[1][kp][o]
                + u.a.partials[2][kp][o] + u.a.partials[3][kp][o] + b1[o];
        u.a.h1f[kp][o] = fmaxf(h, 0.f);
    }
    __syncthreads();
    {   // FC: off[kp][j] = clip(h1 . w2[j] + b2[j])
        int kp = t >> 4, j = t & 15;
        float s = b2[j];
        #pragma unroll
        for (int o = 0; o < 16; ++o) s += u.a.h1f[kp][o] * w2[j * 16 + o];
        s = fminf(fmaxf(s, -MAX_OFFSET), MAX_OFFSET);
        u.a.offs[kp][j] = s;
        int p = j & 7, comp = j >> 3;
        out_off[((size_t)(n0 + kp) * 8 + p) * 2 + comp] = s;
    }
    __syncthreads();

    // ---- phase 2: tap coords/weights once per (kp,p) ----
    if (t < 128) {
        int kp = t >> 3, p = t & 7;
        float px = kw[kp][0] + u.a.offs[kp][p];
        float py = kw[kp][1] + u.a.offs[kp][8 + p];
        float x0f = floorf(px), y0f = floorf(py);
        int x0 = (int)x0f, y0 = (int)y0f;
        float wx1 = px - x0f, wx0 = 1.f - wx1;
        float wy1 = py - y0f, wy0 = 1.f - wy1;
        int x0c = min(max(x0, 0), WW - 1);
        int x1c = min(max(x0 + 1, 0), WW - 1);
        int y0c = min(max(y0, 0), HH - 1);
        int y1c = min(max(y0 + 1, 0), HH - 1);
        float vx0 = (x0 >= 0 && x0 < WW) ? 1.f : 0.f;
        float vx1 = (x0 + 1 >= 0 && x0 + 1 < WW) ? 1.f : 0.f;
        float vy0 = (y0 >= 0 && y0 < HH) ? 1.f : 0.f;
        float vy1 = (y0 + 1 >= 0 && y0 + 1 < HH) ? 1.f : 0.f;
        u.a.tapoff[t][0] = (y0c * WW + x0c) * CC;
        u.a.tapoff[t][1] = (y0c * WW + x1c) * CC;
        u.a.tapoff[t][2] = (y1c * WW + x0c) * CC;
        u.a.tapoff[t][3] = (y1c * WW + x1c) * CC;
        u.a.tapw[t][0] = wx0 * wy0 * vx0 * vy0;
        u.a.tapw[t][1] = wx1 * wy0 * vx1 * vy0;
        u.a.tapw[t][2] = wx0 * wy1 * vx0 * vy1;
        u.a.tapw[t][3] = wx1 * wy1 * vx1 * vy1;
    }
    __syncthreads();

    // ---- phase 3: bilinear -> feats LDS (bf16, swizzled) ----
    {
        int pair = t >> 1, half = t & 1;       // row r = pair = kp*8+p
        const ushort_t* s0 = xb + u.a.tapoff[pair][0];
        const ushort_t* s1 = xb + u.a.tapoff[pair][1];
        const ushort_t* s2 = xb + u.a.tapoff[pair][2];
        const ushort_t* s3 = xb + u.a.tapoff[pair][3];
        float w00 = u.a.tapw[pair][0], w01 = u.a.tapw[pair][1];
        float w10 = u.a.tapw[pair][2], w11 = u.a.tapw[pair][3];
        unsigned rbase = (unsigned)(pair * 256);
        unsigned key   = ((unsigned)(pair & 7)) << 4;
        #pragma unroll
        for (int i = 0; i < 16; ++i) {
            int c = half * 64 + i * 4;
            ushort4_t t0 = *(const ushort4_t*)(s0 + c);
            ushort4_t t1 = *(const ushort4_t*)(s1 + c);
            ushort4_t t2 = *(const ushort4_t*)(s2 + c);
            ushort4_t t3 = *(const ushort4_t*)(s3 + c);
            ushort4_t r4;
            #pragma unroll
            for (int j = 0; j < 4; ++j) {
                float v = bf2f(t0[j]) * w00 + bf2f(t1[j]) * w01
                        + bf2f(t2[j]) * w10 + bf2f(t3[j]) * w11;
                r4[j] = f2bf(v);
            }
            unsigned byte = (rbase + (unsigned)c * 2) ^ key;
            *(ushort4_t*)((char*)feats + byte) = r4;
        }
    }
    __syncthreads();

    // ---- phase 4: GEMM-C (feats x wsf^T -> selu -> g) ----
    for (int rti = 0; rti < 2; ++rti) {
        int rt = wv * 2 + rti;
        int r  = rt * 16 + m;
        unsigned key = ((unsigned)(r & 7)) << 4;
        short8 afr[4];
        #pragma unroll
        for (int kk = 0; kk < 4; ++kk) {
            unsigned byte = ((unsigned)(r * 256 + q * 16 + kk * 64)) ^ key;
            afr[kk] = *(const short8*)((const char*)feats + byte);
        }
        for (int ct = 0; ct < 8; ++ct) {
            const ushort_t* brow = wsf_bf + (ct * 16 + m) * CC + q * 8;
            f32x4 acc = {0.f, 0.f, 0.f, 0.f};
            #pragma unroll
            for (int kk = 0; kk < 4; ++kk) {
                short8 bfr = *(const short8*)(brow + kk * 32);
                acc = __builtin_amdgcn_mfma_f32_16x16x32_bf16(afr[kk], bfr, acc, 0, 0, 0);
            }
            #pragma unroll
            for (int rr = 0; rr < 4; ++rr) {
                float s = acc[rr];
                s = (s > 0.f) ? (SELU_SCALE * s)
                              : (SELU_SCALE * SELU_ALPHA * (expf(s) - 1.f));
                int row = rt * 16 + q * 4 + rr;
                int col = ct * 16 + m;
                unsigned byte = ((unsigned)(row * 256 + col * 2))
                              ^ (((unsigned)((row >> 3) & 7)) << 4);
                *(ushort_t*)((char*)g + byte) = f2bf(s);
            }
        }
    }
    __syncthreads();

    // ---- phase 5: GEMM-D (g x aggT) ----
    f32x4 acc2[2];
    acc2[0] = (f32x4){0.f, 0.f, 0.f, 0.f};
    acc2[1] = (f32x4){0.f, 0.f, 0.f, 0.f};
    const int ctbase = wv * 2;
    for (int kk = 0; kk < 32; ++kk) {
        int p    = kk >> 2;
        int rowA = m * 8 + p;
        unsigned byte = ((unsigned)(rowA * 256 + (kk & 3) * 64 + q * 16))
                      ^ (((unsigned)((rowA >> 3) & 7)) << 4);
        short8 afr = *(const short8*)((const char*)g + byte);
        #pragma unroll
        for (int i = 0; i < 2; ++i) {
            int ct = ctbase + i;
            const ushort_t* brow = aggT_bf + (size_t)(p * CC + ct * 16 + m) * CC
                                 + (kk & 3) * 32 + q * 8;
            short8 bfr = *(const short8*)brow;
            acc2[i] = __builtin_amdgcn_mfma_f32_16x16x32_bf16(afr, bfr, acc2[i], 0, 0, 0);
        }
    }
    #pragma unroll
    for (int i = 0; i < 2; ++i) {
        int ct = ctbase + i;
        #pragma unroll
        for (int rr = 0; rr < 4; ++rr) {
            int n = q * 4 + rr;
            u.dbuf[n * 132 + ct * 16 + m] = acc2[i][rr];
        }
    }
    __syncthreads();

    // ---- L2 norm (16 rows, 16 threads each) ----
    {
        int n = t >> 4, l = t & 15;
        float s = 0.f;
        #pragma unroll
        for (int j = 0; j < 8; ++j) { float v = u.dbuf[n * 132 + l + j * 16]; s += v * v; }
        s += __shfl_xor(s, 1);
        s += __shfl_xor(s, 2);
        s += __shfl_xor(s, 4);
        s += __shfl_xor(s, 8);
        if (l == 0) rn[n] = 1.0f / fmaxf(sqrtf(s), 1e-12f);
    }
    __syncthreads();
    for (int idx = t; idx < 2048; idx += 256) {
        int n = idx >> 7, d = idx & 127;
        out_desc[(size_t)(n0 + n) * CC + d] = u.dbuf[n * 132 + d] * rn[n];
    }
}

// ---------------------------------------------------------------------------
// Fallback: original fused baseline (used only if ws is too small).
__global__ __launch_bounds__(256, 4) void sddh_baseline(
    const float* __restrict__ x, const float* __restrict__ keypoints,
    const float* __restrict__ w1, const float* __restrict__ b1,
    const float* __restrict__ w2, const float* __restrict__ b2,
    const float* __restrict__ wsf, const float* __restrict__ agg,
    float* __restrict__ out_desc, float* __restrict__ out_off)
{
    const int bn = blockIdx.x;
    const int b  = bn / NN;
    const int t  = threadIdx.x;
    const float* xi = x + (size_t)b * CC * HWSZ;

    __shared__ float patch[CC * 9];
    __shared__ float conv_part[16][17];
    __shared__ float h1s[16];
    __shared__ float offs[16];
    __shared__ float feats[CC][NPOS];
    __shared__ float cpart2[CC][NPOS];
    __shared__ float g[CC][NPOS];
    __shared__ float dpart[CC];
    __shared__ float desc[CC];
    __shared__ float sq[128];
    __shared__ float kxy[2];

    if (t == 0) {
        float kx = keypoints[(size_t)bn * 2 + 0];
        float ky = keypoints[(size_t)bn * 2 + 1];
        kxy[0] = (kx * 0.5f + 0.5f) * (float)(WW - 1);
        kxy[1] = (ky * 0.5f + 0.5f) * (float)(HH - 1);
    }
    __syncthreads();
    const float kwx = kxy[0], kwy = kxy[1];
    const int rcx = (int)kwx, rcy = (int)kwy;
    int cx = (int)truncf((float)rcx - 0.5f);
    int cy = (int)truncf((float)rcy - 0.5f);
    cx = min(max(cx, 0), WW - 1 - KS);
    cy = min(max(cy, 0), HH - 1 - KS);

    for (int e = t; e < CC * 9; e += 256) {
        int c = e / 9, k = e % 9;
        int dy = k / 3, dx = k % 3;
        patch[e] = xi[(size_t)c * HWSZ + (cy + dy) * WW + (cx + dx)];
    }
    __syncthreads();
    {
        int o = t & 15, j = t >> 4;
        float acc = 0.f;
        const float* wo = w1 + o * (CC * 9);
        for (int e = j; e < CC * 9; e += 16) acc += patch[e] * wo[e];
        conv_part[o][j] = acc;
    }
    __syncthreads();
    if (t < 16) {
        float s = b1[t];
        #pragma unroll
        for (int j = 0; j < 16; j++) s += conv_part[t][j];
        h1s[t] = fmaxf(s, 0.f);
    }
    __syncthreads();
    if (t < 16) {
        float s = b2[t];
        #pragma unroll
        for (int k = 0; k < 16; k++) s += h1s[k] * w2[t * 16 + k];
        s = fminf(fmaxf(s, -MAX_OFFSET), MAX_OFFSET);
        offs[t] = s;
        int idx = (t < 8) ? (bn * 16 + t * 2) : (bn * 16 + (t - 8) * 2 + 1);
        out_off[idx] = s;
    }
    __syncthreads();

    for (int e = t; e < CC * NPOS; e += 256) {
        int c = e & 127, p = e >> 7;
        float px = kwx + offs[p];
        float py = kwy + offs[8 + p];
        float x0f = floorf(px), y0f = floorf(py);
        int x0 = (int)x0f, y0 = (int)y0f;
        float wx1 = px - x0f, wx0 = 1.f - wx1;
        float wy1 = py - y0f, wy0 = 1.f - wy1;
        const float* xc = xi + (size_t)c * HWSZ;
        int x0c = min(max(x0, 0), WW - 1);
        int x1c = min(max(x0 + 1, 0), WW - 1);
        int y0c = min(max(y0, 0), HH - 1);
        int y1c = min(max(y0 + 1, 0), HH - 1);
        float vx0 = (x0 >= 0 && x0 < WW) ? 1.f : 0.f;
        float vx1 = (x0 + 1 >= 0 && x0 + 1 < WW) ? 1.f : 0.f;
        float vy0 = (y0 >= 0 && y0 < HH) ? 1.f : 0.f;
        float vy1 = (y0 + 1 >= 0 && y0 + 1 < HH) ? 1.f : 0.f;
        float v = 0.f;
        v += xc[y0c * WW + x0c] * (wx0 * wy0) * (vx0 * vy0);
        v += xc[y0c * WW + x1c] * (wx1 * wy0) * (vx1 * vy0);
        v += xc[y1c * WW + x0c] * (wx0 * wy1) * (vx0 * vy1);
        v += xc[y1c * WW + x1c] * (wx1 * wy1) * (vx1 * vy1);
        feats[c][p] = v;
    }
    __syncthreads();
    {
        int d = t & 127, chalf = t >> 7;
        float acc[NPOS];
        #pragma unroll
        for (int p = 0; p < NPOS; p++) acc[p] = 0.f;
        const float* wrow = wsf + d * CC;
        int c0 = chalf * 64;
        for (int c = c0; c < c0 + 64; c++) {
            float wv = wrow[c];
            #pragma unroll
            for (int p = 0; p < NPOS; p++) acc[p] += feats[c][p] * wv;
        }
        if (chalf) {
            #pragma unroll
            for (int p = 0; p < NPOS; p++) cpart2[d][p] = acc[p];
        }
        __syncthreads();
        if (!chalf) {
            #pragma unroll
            for (int p = 0; p < NPOS; p++) {
                float s = acc[p] + cpart2[d][p];
                s = (s > 0.f) ? (SELU_SCALE * s)
                              : (SELU_SCALE * SELU_ALPHA * (expf(s) - 1.f));
                g[d][p] = s;
            }
        }
    }
    __syncthreads();
    {
        int d = t & 127, half = t >> 7;
        float acc = 0.f;
        int p0 = half * 4;
        for (int p = p0; p < p0 + 4; p++) {
            const float* ap = agg + (size_t)p * CC * CC;
            for (int e = 0; e < CC; e++) acc += g[e][p] * ap[e * CC + d];
        }
        if (half) dpart[d] = acc;
        __syncthreads();
        if (!half) {
            float v = acc + dpart[d];
            desc[d] = v;
            sq[d] = v * v;
        }
    }
    __syncthreads();
    if (t < 64) sq[t] += sq[t + 64]; __syncthreads();
    if (t < 32) sq[t] += sq[t + 32]; __syncthreads();
    if (t < 16) sq[t] += sq[t + 16]; __syncthreads();
    if (t < 8)  sq[t] += sq[t + 8];  __syncthreads();
    if (t < 4)  sq[t] += sq[t + 4];  __syncthreads();
    if (t < 2)  sq[t] += sq[t + 2];  __syncthreads();
    if (t == 0) sq[0] = fmaxf(sqrtf(sq[0] + sq[1]), 1e-12f);
    __syncthreads();
    if (t < 128) out_desc[(size_t)bn * CC + t] = desc[t] / sq[0];
}

// ---------------------------------------------------------------------------
extern "C" void kernel_launch(void* const* d_in, const int* in_sizes, int n_in,
                              void* d_out, int out_size, void* d_ws, size_t ws_size,
                              hipStream_t stream) {
    const float* x    = (const float*)d_in[0];
    const float* kpts = (const float*)d_in[1];
    const float* w1   = (const float*)d_in[2];
    const float* b1   = (const float*)d_in[3];
    const float* w2   = (const float*)d_in[4];
    const float* b2   = (const float*)d_in[5];
    const float* wsf  = (const float*)d_in[6];
    const float* agg  = (const float*)d_in[7];

    float* out_desc = (float*)d_out;
    float* out_off  = (float*)d_out + (size_t)BB * NN * CC;

    if (ws_size < WS_NEEDED) {
        hipLaunchKernelGGL(sddh_baseline, dim3(BB * NN), dim3(256), 0, stream,
                           x, kpts, w1, b1, w2, b2, wsf, agg, out_desc, out_off);
        return;
    }

    ushort_t* xt      = (ushort_t*)d_ws;
    ushort_t* wsf_bf  = xt + XT_ELEMS;
    ushort_t* aggT_bf = wsf_bf + WSFBF_ELEMS;
    ushort_t* w1t_bf  = aggT_bf + AGGT_ELEMS;

    hipLaunchKernelGGL(k0p, dim3(BB * HH * 4 + 512), dim3(256), 0, stream,
                       x, xt, wsf, agg, w1, wsf_bf, aggT_bf, w1t_bf);
    hipLaunchKernelGGL(k14_fused, dim3(BB * NN / 16), dim3(256), 0, stream,
                       xt, kpts, w1t_bf, b1, w2, b2, wsf_bf, aggT_bf,
                       out_desc, out_off);
}